// Round 8
// baseline (150.309 us; speedup 1.0000x reference)
//
#include <hip/hip_runtime.h>
#include <stdint.h>

#define N_NODES 50000
#define N_EDGES 800000
#define IN_CH 128
#define HIDDEN 16
#define OUT_CH 64
#define G 4                              // buckets per node
#define GCAP 32                          // slots per bucket (1 x 64B line)
#define MAXOVF 4096

#define LB ((N_NODES + 31) / 32)        // 1563 linear1-role blocks
#define EB ((N_EDGES + 255) / 256)      // 3125 bucket-role blocks

// ---------------------------------------------------------------------------
// cnt[N*G] = 0, ovf_cnt = 0, int64/int32 detect -- one launch.
// ---------------------------------------------------------------------------
__global__ __launch_bounds__(256) void k_init(
    int* __restrict__ cnt, int* __restrict__ ovf_cnt,
    const int* __restrict__ ei, int* __restrict__ flag)
{
    const int i = blockIdx.x * 256 + threadIdx.x;
    if (i < N_NODES * G) cnt[i] = 0;
    if (i == 0) {
        *ovf_cnt = 0;
        int is64 = 1;
        for (int j = 0; j < 64; ++j) {
            if (ei[2 * j + 1] != 0) { is64 = 0; break; }
        }
        *flag = is64;
    }
}

// ---------------------------------------------------------------------------
// Fused: blocks [0,LB) compute y1 = x@W1l, z1 = x@W1r  (LDS-tiled);
//        blocks [LB,LB+EB) bin edges straight into bucket-CSR:
//          pos = atomicAdd(&cnt[dst*G + (e&3)], 1)
//          pos < GCAP ? row[bucket*GCAP+pos] = src : overflow list
// cnt keeps the TRUE degree (uncapped); row is immediately gather-ready.
// ---------------------------------------------------------------------------
__global__ __launch_bounds__(256) void k_build(
    const float* __restrict__ x,
    const float* __restrict__ W1l, const float* __restrict__ W1r,
    float* __restrict__ y1, float* __restrict__ z1,
    const int* __restrict__ ei, int* __restrict__ cnt,
    uint16_t* __restrict__ row, int2* __restrict__ ovf, int* __restrict__ ovf_cnt,
    const int* __restrict__ flag)
{
    __shared__ float sW[IN_CH][33];        // cols 0-15: W1l, 16-31: W1r (+pad)
    __shared__ float sx[32][IN_CH + 1];
    const int t = threadIdx.x;

    if (blockIdx.x >= LB) {
        // ---- binning role ----
        const int e = (blockIdx.x - LB) * 256 + t;
        if (e >= N_EDGES) return;
        const int is64 = *flag;
        int src, dst;
        if (is64) { src = ei[2 * e]; dst = ei[2 * (N_EDGES + e)]; }
        else      { src = ei[e];     dst = ei[N_EDGES + e]; }
        const int b = dst * G + (e & (G - 1));
        const int pos = atomicAdd(&cnt[b], 1);
        if (pos < GCAP) {
            row[b * GCAP + pos] = (uint16_t)src;
        } else {
            const int o = atomicAdd(ovf_cnt, 1);
            if (o < MAXOVF) ovf[o] = make_int2(dst, src);
        }
        return;
    }

    // ---- linear1 role ----
    for (int i = t; i < IN_CH * HIDDEN; i += 256) {
        int k = i / HIDDEN, c = i % HIDDEN;
        sW[k][c]      = W1l[i];
        sW[k][c + 16] = W1r[i];
    }

    const int node0 = blockIdx.x * 32;
    for (int i = t; i < 32 * (IN_CH / 4); i += 256) {
        int r    = i / (IN_CH / 4);
        int col4 = i % (IN_CH / 4);
        int node = node0 + r;
        float4 v = make_float4(0.f, 0.f, 0.f, 0.f);
        if (node < N_NODES)
            v = ((const float4*)x)[node * (IN_CH / 4) + col4];
        sx[r][col4 * 4 + 0] = v.x;
        sx[r][col4 * 4 + 1] = v.y;
        sx[r][col4 * 4 + 2] = v.z;
        sx[r][col4 * 4 + 3] = v.w;
    }
    __syncthreads();

    const int r   = t & 31;
    const int og  = t >> 5;
    const int node = node0 + r;

    float acc[4] = {0.f, 0.f, 0.f, 0.f};
    for (int k = 0; k < IN_CH; ++k) {
        float xv = sx[r][k];
        #pragma unroll
        for (int j = 0; j < 4; ++j)
            acc[j] += xv * sW[k][og * 4 + j];
    }

    if (node < N_NODES) {
        #pragma unroll
        for (int j = 0; j < 4; ++j) {
            int oc = og * 4 + j;
            if (oc < HIDDEN) y1[node * HIDDEN + oc]            = acc[j];
            else             z1[node * HIDDEN + (oc - HIDDEN)] = acc[j];
        }
    }
}

// ---------------------------------------------------------------------------
// Gather layer 1 (bucket-CSR, no chains): wave per node, 4 groups of 16
// lanes; group g sums its bucket with 4-wide independent row gathers.
// Fused h = relu(mean + b1 + z1) written in place over z1.
// ---------------------------------------------------------------------------
__global__ __launch_bounds__(256) void k_gather_h(
    const int* __restrict__ cnt, const uint16_t* __restrict__ row,
    const int2* __restrict__ ovf, const int* __restrict__ ovf_cnt,
    const float* __restrict__ y1, float* __restrict__ z1h,
    const float* __restrict__ b1l)
{
    const int lane = threadIdx.x & 63;
    const int wid  = threadIdx.x >> 6;
    const int n = blockIdx.x * 4 + wid;     // 12500 * 4 = exactly 50000
    const int g = lane >> 4;
    const int c = lane & 15;

    const int b = n * G + g;
    const int dgr = cnt[b];                 // true (uncapped) bucket degree
    const int dg  = dgr < GCAP ? dgr : GCAP;
    const uint16_t* rp = row + b * GCAP;

    float s = 0.f;
    int i = 0;
    for (; i + 4 <= dg; i += 4) {
        const int s0 = rp[i + 0], s1 = rp[i + 1];
        const int s2 = rp[i + 2], s3 = rp[i + 3];
        s += y1[s0 * HIDDEN + c] + y1[s1 * HIDDEN + c]
           + y1[s2 * HIDDEN + c] + y1[s3 * HIDDEN + c];
    }
    for (; i < dg; ++i)
        s += y1[(int)rp[i] * HIDDEN + c];

    const int on = *ovf_cnt;                // 0 in practice (cached broadcast)
    if (on > 0 && g == 0) {
        for (int o = 0; o < on && o < MAXOVF; ++o) {
            const int2 p = ovf[o];
            if (p.x == n) s += y1[p.y * HIDDEN + c];
        }
    }

    float st = s; int dt = dgr;
    st += __shfl_xor(st, 16); st += __shfl_xor(st, 32);
    dt += __shfl_xor(dt, 16); dt += __shfl_xor(dt, 32);

    if (g == 0) {
        const float m = st / fmaxf((float)dt, 1.0f);
        const size_t idx = (size_t)n * HIDDEN + c;
        z1h[idx] = fmaxf(m + b1l[c] + z1h[idx], 0.f);   // in-place z1 -> h
    }
}

// ---------------------------------------------------------------------------
// Fused gather layer 2 + output (bucket-CSR):
//   mean2 via 4-wide independent h-row gathers, then
//   out = log_softmax(mean2 @ W2l + b2l + h @ W2r), lane = out channel.
// ---------------------------------------------------------------------------
__global__ __launch_bounds__(256) void k_out(
    const int* __restrict__ cnt, const uint16_t* __restrict__ row,
    const int2* __restrict__ ovf, const int* __restrict__ ovf_cnt,
    const float* __restrict__ h,
    const float* __restrict__ W2l, const float* __restrict__ b2l,
    const float* __restrict__ W2r,
    float* __restrict__ out)
{
    __shared__ float sW[HIDDEN][2][OUT_CH];   // 8 KiB
    __shared__ float sm[4][HIDDEN];
    __shared__ float sh[4][HIDDEN];
    const int t = threadIdx.x;
    for (int i = t; i < HIDDEN * OUT_CH; i += 256) {
        int k = i / OUT_CH, c2 = i % OUT_CH;
        sW[k][0][c2] = W2l[i];
        sW[k][1][c2] = W2r[i];
    }

    const int lane = t & 63;
    const int wid  = t >> 6;
    const int n = blockIdx.x * 4 + wid;
    const int g = lane >> 4;
    const int c = lane & 15;

    const int b = n * G + g;
    const int dgr = cnt[b];
    const int dg  = dgr < GCAP ? dgr : GCAP;
    const uint16_t* rp = row + b * GCAP;

    float s = 0.f;
    int i = 0;
    for (; i + 4 <= dg; i += 4) {
        const int s0 = rp[i + 0], s1 = rp[i + 1];
        const int s2 = rp[i + 2], s3 = rp[i + 3];
        s += h[s0 * HIDDEN + c] + h[s1 * HIDDEN + c]
           + h[s2 * HIDDEN + c] + h[s3 * HIDDEN + c];
    }
    for (; i < dg; ++i)
        s += h[(int)rp[i] * HIDDEN + c];

    const int on = *ovf_cnt;
    if (on > 0 && g == 0) {
        for (int o = 0; o < on && o < MAXOVF; ++o) {
            const int2 p = ovf[o];
            if (p.x == n) s += h[p.y * HIDDEN + c];
        }
    }

    float st = s; int dt = dgr;
    st += __shfl_xor(st, 16); st += __shfl_xor(st, 32);
    dt += __shfl_xor(dt, 16); dt += __shfl_xor(dt, 32);
    if (g == 0) {
        sm[wid][c] = st / fmaxf((float)dt, 1.0f);
        sh[wid][c] = h[(size_t)n * HIDDEN + c];
    }
    __syncthreads();

    float acc = b2l[lane];
    #pragma unroll
    for (int k = 0; k < HIDDEN; ++k)
        acc += sm[wid][k] * sW[k][0][lane] + sh[wid][k] * sW[k][1][lane];

    float mx = acc;
    #pragma unroll
    for (int off = 32; off > 0; off >>= 1)
        mx = fmaxf(mx, __shfl_xor(mx, off));
    float ex = expf(acc - mx);
    float sum = ex;
    #pragma unroll
    for (int off = 32; off > 0; off >>= 1)
        sum += __shfl_xor(sum, off);

    out[(size_t)n * OUT_CH + lane] = acc - mx - logf(sum);
}

// ---------------------------------------------------------------------------
extern "C" void kernel_launch(void* const* d_in, const int* in_sizes, int n_in,
                              void* d_out, int out_size, void* d_ws, size_t ws_size,
                              hipStream_t stream)
{
    const float* x   = (const float*)d_in[0];
    const float* W1l = (const float*)d_in[1];
    const float* b1l = (const float*)d_in[2];
    const float* W1r = (const float*)d_in[3];
    const float* W2l = (const float*)d_in[4];
    const float* b2l = (const float*)d_in[5];
    const float* W2r = (const float*)d_in[6];
    const int*   ei  = (const int*)d_in[7];
    float* out = (float*)d_out;

    const size_t NH = (size_t)N_NODES * HIDDEN;           // 800000
    // layout (ws ~256MB, using ~21MB):
    float* bufA      = (float*)d_ws;                      // y1        3.2 MB
    float* bufB      = bufA + NH;                         // z1 -> h   3.2 MB
    uint16_t* row    = (uint16_t*)(bufB + NH);            // [N*G*GCAP] 12.8 MB (64B-aligned)
    int* cnt         = (int*)(row + (size_t)N_NODES * G * GCAP); // [N*G] 0.8 MB
    int2* ovf        = (int2*)(cnt + N_NODES * G);        // [MAXOVF]  32 KB (8B-aligned)
    int* ovf_cnt     = (int*)(ovf + MAXOVF);
    int* flag        = ovf_cnt + 1;

    k_init<<<(N_NODES * G + 255) / 256, 256, 0, stream>>>(cnt, ovf_cnt, ei, flag);

    // fused: linear1 (blocks 0..LB-1)  +  edge binning (blocks LB..LB+EB-1)
    k_build<<<LB + EB, 256, 0, stream>>>(x, W1l, W1r, bufA, bufB, ei, cnt,
                                         row, ovf, ovf_cnt, flag);

    // h = relu(mean(y1)+b1+z1) in place over bufB
    k_gather_h<<<N_NODES / 4, 256, 0, stream>>>(cnt, row, ovf, ovf_cnt,
                                                bufA, bufB, b1l);

    // fused gather2 + linear2 + log_softmax
    k_out<<<N_NODES / 4, 256, 0, stream>>>(cnt, row, ovf, ovf_cnt, bufB,
                                           W2l, b2l, W2r, out);
}

// Round 9
// 141.759 us; speedup vs baseline: 1.0603x; 1.0603x over previous
//
#include <hip/hip_runtime.h>
#include <stdint.h>

#define N_NODES 50000
#define N_EDGES 800000
#define IN_CH 128
#define HIDDEN 16
#define OUT_CH 64
#define NCHAIN 8
#define ROWCAP 48                        // per-node CSR slots (96B region)
#define MAXOVF 4096

#define LB ((N_NODES + 31) / 32)        // 1563 linear1-role blocks
#define EB ((N_EDGES + 255) / 256)      // 3125 link-role blocks

// ---------------------------------------------------------------------------
// head[NCHAIN*N] = -1, ovf_cnt = 0, int64/int32 detect -- one launch.
// ---------------------------------------------------------------------------
__global__ __launch_bounds__(256) void k_init(
    int* __restrict__ head, int* __restrict__ ovf_cnt,
    const int* __restrict__ ei, int* __restrict__ flag)
{
    const int i = blockIdx.x * 256 + threadIdx.x;
    if (i < NCHAIN * N_NODES) head[i] = -1;
    if (i == 0) {
        *ovf_cnt = 0;
        int is64 = 1;
        for (int j = 0; j < 64; ++j) {
            if (ei[2 * j + 1] != 0) { is64 = 0; break; }
        }
        *flag = is64;
    }
}

// ---------------------------------------------------------------------------
// Fused: blocks [0,LB) compute y1 = x@W1l, z1 = x@W1r  (LDS-tiled);
//        blocks [LB,LB+EB) build 8-way-split per-dst linked lists.
// Invariant (R8 lesson): the ONLY random-address op is the atomic; next/src16
// stores are edge-indexed and fully coalesced.
// ---------------------------------------------------------------------------
__global__ __launch_bounds__(256) void k_build(
    const float* __restrict__ x,
    const float* __restrict__ W1l, const float* __restrict__ W1r,
    float* __restrict__ y1, float* __restrict__ z1,
    const int* __restrict__ ei, int* __restrict__ head,
    int* __restrict__ next, uint16_t* __restrict__ src16,
    const int* __restrict__ flag)
{
    __shared__ float sW[IN_CH][33];        // cols 0-15: W1l, 16-31: W1r (+pad)
    __shared__ float sx[32][IN_CH + 1];
    const int t = threadIdx.x;

    if (blockIdx.x >= LB) {
        // ---- link role ----
        const int e = (blockIdx.x - LB) * 256 + t;
        if (e >= N_EDGES) return;
        const int is64 = *flag;
        int src, dst;
        if (is64) { src = ei[2 * e]; dst = ei[2 * (N_EDGES + e)]; }
        else      { src = ei[e];     dst = ei[N_EDGES + e]; }
        const int prev = atomicExch(&head[(e & (NCHAIN - 1)) * N_NODES + dst], e);
        next[e]  = prev;
        src16[e] = (uint16_t)src;
        return;
    }

    // ---- linear1 role ----
    for (int i = t; i < IN_CH * HIDDEN; i += 256) {
        int k = i / HIDDEN, c = i % HIDDEN;
        sW[k][c]      = W1l[i];
        sW[k][c + 16] = W1r[i];
    }

    const int node0 = blockIdx.x * 32;
    for (int i = t; i < 32 * (IN_CH / 4); i += 256) {
        int r    = i / (IN_CH / 4);
        int col4 = i % (IN_CH / 4);
        int node = node0 + r;
        float4 v = make_float4(0.f, 0.f, 0.f, 0.f);
        if (node < N_NODES)
            v = ((const float4*)x)[node * (IN_CH / 4) + col4];
        sx[r][col4 * 4 + 0] = v.x;
        sx[r][col4 * 4 + 1] = v.y;
        sx[r][col4 * 4 + 2] = v.z;
        sx[r][col4 * 4 + 3] = v.w;
    }
    __syncthreads();

    const int r    = t & 31;
    const int og   = t >> 5;
    const int node = node0 + r;

    float acc[4] = {0.f, 0.f, 0.f, 0.f};
    for (int k = 0; k < IN_CH; ++k) {
        float xv = sx[r][k];
        #pragma unroll
        for (int j = 0; j < 4; ++j)
            acc[j] += xv * sW[k][og * 4 + j];
    }

    if (node < N_NODES) {
        #pragma unroll
        for (int j = 0; j < 4; ++j) {
            int oc = og * 4 + j;
            if (oc < HIDDEN) y1[node * HIDDEN + oc]            = acc[j];
            else             z1[node * HIDDEN + (oc - HIDDEN)] = acc[j];
        }
    }
}

// ---------------------------------------------------------------------------
// Materialize per-node CSR rows from the 8 chains.
// 8 lanes per node, one chain each: count pass -> shfl prefix -> store pass.
// Stores land in the node's OWN 96B region (dense across the block) + cnt.
// Overflow beyond ROWCAP (P ~ 1e-11 per node) -> global list.
// ---------------------------------------------------------------------------
__global__ __launch_bounds__(256) void k_mat(
    const int* __restrict__ head, const int* __restrict__ next,
    const uint16_t* __restrict__ src16,
    uint16_t* __restrict__ row, int* __restrict__ cnt,
    int2* __restrict__ ovf, int* __restrict__ ovf_cnt)
{
    const int lane = threadIdx.x & 63;
    const int n = blockIdx.x * 32 + (threadIdx.x >> 3);  // 8 lanes per node
    const int l = lane & 7;                              // chain id
    if (n >= N_NODES) return;

    // pass 1: count my chain
    int c1 = 0;
    {
        int e = head[l * N_NODES + n];
        while (e >= 0) { ++c1; e = next[e]; }
    }
    // group-local inclusive prefix over 8 lanes
    int incl = c1;
    #pragma unroll
    for (int off = 1; off < 8; off <<= 1) {
        int u = __shfl_up(incl, off);
        if (l >= off) incl += u;
    }
    const int tot  = __shfl(incl, lane | 7);   // group total = true degree
    int k = incl - c1;                         // my exclusive base

    // pass 2: emit (next/src16 now cache-hot)
    {
        int e = head[l * N_NODES + n];
        while (e >= 0) {
            const int s = src16[e];
            if (k < ROWCAP) {
                row[n * ROWCAP + k] = (uint16_t)s;
            } else {
                const int o = atomicAdd(ovf_cnt, 1);
                if (o < MAXOVF) ovf[o] = make_int2(n, s);
            }
            ++k;
            e = next[e];
        }
    }
    if (l == 0) cnt[n] = tot;
}

// ---------------------------------------------------------------------------
// Gather layer 1 (node CSR, no chains): wave per node, 4 groups of 16 lanes;
// group g sums slots g, g+4, g+8, ... (independent loads).
// Fused h = relu(mean + b1 + z1) written in place over z1.
// ---------------------------------------------------------------------------
__global__ __launch_bounds__(256) void k_gather_h(
    const int* __restrict__ cnt, const uint16_t* __restrict__ row,
    const int2* __restrict__ ovf, const int* __restrict__ ovf_cnt,
    const float* __restrict__ y1, float* __restrict__ z1h,
    const float* __restrict__ b1l)
{
    const int lane = threadIdx.x & 63;
    const int wid  = threadIdx.x >> 6;
    const int n = blockIdx.x * 4 + wid;     // 12500 * 4 = exactly 50000
    const int g = lane >> 4;
    const int c = lane & 15;

    const int dgr   = cnt[n];
    const int slots = dgr < ROWCAP ? dgr : ROWCAP;
    const uint16_t* rp = row + n * ROWCAP;

    float s = 0.f;
    for (int i = g; i < slots; i += 4)
        s += y1[(int)rp[i] * HIDDEN + c];

    if (dgr > ROWCAP && g == 0) {
        const int on = *ovf_cnt;
        for (int o = 0; o < on && o < MAXOVF; ++o) {
            const int2 p = ovf[o];
            if (p.x == n) s += y1[p.y * HIDDEN + c];
        }
    }

    float st = s;
    st += __shfl_xor(st, 16); st += __shfl_xor(st, 32);

    if (g == 0) {
        const float m = st / fmaxf((float)dgr, 1.0f);
        const size_t idx = (size_t)n * HIDDEN + c;
        z1h[idx] = fmaxf(m + b1l[c] + z1h[idx], 0.f);   // in-place z1 -> h
    }
}

// ---------------------------------------------------------------------------
// Fused gather layer 2 + output (node CSR):
//   mean2 via striped independent h-row gathers, then
//   out = log_softmax(mean2 @ W2l + b2l + h @ W2r), lane = out channel.
// ---------------------------------------------------------------------------
__global__ __launch_bounds__(256) void k_out(
    const int* __restrict__ cnt, const uint16_t* __restrict__ row,
    const int2* __restrict__ ovf, const int* __restrict__ ovf_cnt,
    const float* __restrict__ h,
    const float* __restrict__ W2l, const float* __restrict__ b2l,
    const float* __restrict__ W2r,
    float* __restrict__ out)
{
    __shared__ float sW[HIDDEN][2][OUT_CH];   // 8 KiB
    __shared__ float sm[4][HIDDEN];
    __shared__ float sh[4][HIDDEN];
    const int t = threadIdx.x;
    for (int i = t; i < HIDDEN * OUT_CH; i += 256) {
        int k = i / OUT_CH, c2 = i % OUT_CH;
        sW[k][0][c2] = W2l[i];
        sW[k][1][c2] = W2r[i];
    }

    const int lane = t & 63;
    const int wid  = t >> 6;
    const int n = blockIdx.x * 4 + wid;
    const int g = lane >> 4;
    const int c = lane & 15;

    const int dgr   = cnt[n];
    const int slots = dgr < ROWCAP ? dgr : ROWCAP;
    const uint16_t* rp = row + n * ROWCAP;

    float s = 0.f;
    for (int i = g; i < slots; i += 4)
        s += h[(int)rp[i] * HIDDEN + c];

    if (dgr > ROWCAP && g == 0) {
        const int on = *ovf_cnt;
        for (int o = 0; o < on && o < MAXOVF; ++o) {
            const int2 p = ovf[o];
            if (p.x == n) s += h[p.y * HIDDEN + c];
        }
    }

    float st = s;
    st += __shfl_xor(st, 16); st += __shfl_xor(st, 32);
    if (g == 0) {
        sm[wid][c] = st / fmaxf((float)dgr, 1.0f);
        sh[wid][c] = h[(size_t)n * HIDDEN + c];
    }
    __syncthreads();

    float acc = b2l[lane];
    #pragma unroll
    for (int k = 0; k < HIDDEN; ++k)
        acc += sm[wid][k] * sW[k][0][lane] + sh[wid][k] * sW[k][1][lane];

    float mx = acc;
    #pragma unroll
    for (int off = 32; off > 0; off >>= 1)
        mx = fmaxf(mx, __shfl_xor(mx, off));
    float ex = expf(acc - mx);
    float sum = ex;
    #pragma unroll
    for (int off = 32; off > 0; off >>= 1)
        sum += __shfl_xor(sum, off);

    out[(size_t)n * OUT_CH + lane] = acc - mx - logf(sum);
}

// ---------------------------------------------------------------------------
extern "C" void kernel_launch(void* const* d_in, const int* in_sizes, int n_in,
                              void* d_out, int out_size, void* d_ws, size_t ws_size,
                              hipStream_t stream)
{
    const float* x   = (const float*)d_in[0];
    const float* W1l = (const float*)d_in[1];
    const float* b1l = (const float*)d_in[2];
    const float* W1r = (const float*)d_in[3];
    const float* W2l = (const float*)d_in[4];
    const float* b2l = (const float*)d_in[5];
    const float* W2r = (const float*)d_in[6];
    const int*   ei  = (const int*)d_in[7];
    float* out = (float*)d_out;

    const size_t NH = (size_t)N_NODES * HIDDEN;           // 800000
    // layout (all sub-arrays multiple-of-16 bytes; ws ~256MB, using ~18MB)
    int*   next   = (int*)d_ws;                           // [N_EDGES]   3.2 MB
    float* bufA   = (float*)(next + N_EDGES);             // y1          3.2 MB
    float* bufB   = bufA + NH;                            // z1 -> h     3.2 MB
    int*   head   = (int*)(bufB + NH);                    // [8*N]       1.6 MB
    int*   cnt    = head + NCHAIN * N_NODES;              // [N]         0.2 MB
    uint16_t* src16 = (uint16_t*)(cnt + N_NODES);         // [N_EDGES]   1.6 MB
    uint16_t* row   = src16 + N_EDGES;                    // [N*ROWCAP]  4.8 MB
    int2* ovf     = (int2*)(row + (size_t)N_NODES * ROWCAP); // [MAXOVF] 32 KB
    int* ovf_cnt  = (int*)(ovf + MAXOVF);
    int* flag     = ovf_cnt + 1;

    k_init<<<(NCHAIN * N_NODES + 255) / 256, 256, 0, stream>>>(head, ovf_cnt, ei, flag);

    // fused: linear1 (blocks 0..LB-1)  +  chain build (blocks LB..LB+EB-1)
    k_build<<<LB + EB, 256, 0, stream>>>(x, W1l, W1r, bufA, bufB, ei, head,
                                         next, src16, flag);

    // chains -> per-node CSR rows (coalesced node-owned regions)
    k_mat<<<(N_NODES + 31) / 32, 256, 0, stream>>>(head, next, src16, row, cnt,
                                                   ovf, ovf_cnt);

    // h = relu(mean(y1)+b1+z1) in place over bufB
    k_gather_h<<<N_NODES / 4, 256, 0, stream>>>(cnt, row, ovf, ovf_cnt,
                                                bufA, bufB, b1l);

    // fused gather2 + linear2 + log_softmax
    k_out<<<N_NODES / 4, 256, 0, stream>>>(cnt, row, ovf, ovf_cnt, bufB,
                                           W2l, b2l, W2r, out);
}

// Round 10
// 113.137 us; speedup vs baseline: 1.3286x; 1.2530x over previous
//
#include <hip/hip_runtime.h>
#include <stdint.h>

#define N_NODES 50000
#define N_EDGES 800000
#define IN_CH 128
#define HIDDEN 16
#define OUT_CH 64
#define ROWCAP 48                        // per-node CSR slots (96B region)
#define MAXOVF 4096
#define NB 196                           // coarse buckets (dst>>8), 256 nodes each
#define BCAP 8192                        // slots per bucket (avg 4082, +64 sigma)

#define LB ((N_NODES + 31) / 32)         // 1563 linear1-role blocks
#define PB ((N_EDGES + 1023) / 1024)     // 782 partition-role blocks (1024 edges each)

// ---------------------------------------------------------------------------
// gcur[]=0, counters=0, int64/int32 detect -- one tiny launch.
// ---------------------------------------------------------------------------
__global__ __launch_bounds__(256) void k_init(
    int* __restrict__ gcur, int* __restrict__ sc, const int* __restrict__ ei)
{
    const int t = threadIdx.x;
    if (t < 256) gcur[t] = 0;
    if (t == 0) {
        sc[0] = 0;          // spill_cnt
        sc[1] = 0;          // ovf_cnt
        int is64 = 1;
        for (int j = 0; j < 64; ++j) {
            if (ei[2 * j + 1] != 0) { is64 = 0; break; }
        }
        sc[2] = is64;       // flag
    }
}

// ---------------------------------------------------------------------------
// Fused: blocks [0,LB) -> y1 = x@W1l, z1 = x@W1r (LDS-tiled);
//        blocks [LB,LB+PB) -> partition 1024 edges into coarse buckets:
//          LDS histogram -> 1 global atomicAdd per BIN (run reservation)
//          -> packed 4B writes in contiguous runs.
// R8 lesson preserved: no random store depends on a per-edge global atomic.
// ---------------------------------------------------------------------------
__global__ __launch_bounds__(256) void k_build(
    const float* __restrict__ x,
    const float* __restrict__ W1l, const float* __restrict__ W1r,
    float* __restrict__ y1, float* __restrict__ z1,
    const int* __restrict__ ei,
    int* __restrict__ bucket, int* __restrict__ gcur,
    int2* __restrict__ spill, int* __restrict__ sc)
{
    __shared__ float sW[IN_CH][33];        // cols 0-15: W1l, 16-31: W1r (+pad)
    __shared__ float sx[32][IN_CH + 1];
    __shared__ int hist[NB], cur[NB], base[NB];
    const int t = threadIdx.x;

    if (blockIdx.x >= LB) {
        // ---- partition role ----
        const int e0 = (blockIdx.x - LB) * 1024;
        for (int i = t; i < NB; i += 256) { hist[i] = 0; cur[i] = 0; }
        __syncthreads();

        const int is64 = sc[2];
        int srcs[4], dsts[4];
        #pragma unroll
        for (int k = 0; k < 4; ++k) {
            const int e = e0 + t + k * 256;
            int src = 0, dst = -1;
            if (e < N_EDGES) {
                if (is64) { src = ei[2 * e]; dst = ei[2 * (N_EDGES + e)]; }
                else      { src = ei[e];     dst = ei[N_EDGES + e]; }
                atomicAdd(&hist[dst >> 8], 1);            // LDS atomic
            }
            srcs[k] = src; dsts[k] = dst;
        }
        __syncthreads();

        for (int i = t; i < NB; i += 256)
            base[i] = (hist[i] > 0) ? atomicAdd(&gcur[i], hist[i]) : 0;
        __syncthreads();

        #pragma unroll
        for (int k = 0; k < 4; ++k) {
            if (dsts[k] >= 0) {
                const int bin = dsts[k] >> 8;
                const int loc = atomicAdd(&cur[bin], 1);   // LDS atomic
                const int pos = base[bin] + loc;
                if (pos < BCAP) {
                    bucket[bin * BCAP + pos] = ((dsts[k] & 255) << 16) | srcs[k];
                } else {                                   // ~impossible
                    const int o = atomicAdd(&sc[0], 1);
                    if (o < MAXOVF) spill[o] = make_int2(dsts[k], srcs[k]);
                }
            }
        }
        return;
    }

    // ---- linear1 role ----
    for (int i = t; i < IN_CH * HIDDEN; i += 256) {
        int k = i / HIDDEN, c = i % HIDDEN;
        sW[k][c]      = W1l[i];
        sW[k][c + 16] = W1r[i];
    }

    const int node0 = blockIdx.x * 32;
    for (int i = t; i < 32 * (IN_CH / 4); i += 256) {
        int r    = i / (IN_CH / 4);
        int col4 = i % (IN_CH / 4);
        int node = node0 + r;
        float4 v = make_float4(0.f, 0.f, 0.f, 0.f);
        if (node < N_NODES)
            v = ((const float4*)x)[node * (IN_CH / 4) + col4];
        sx[r][col4 * 4 + 0] = v.x;
        sx[r][col4 * 4 + 1] = v.y;
        sx[r][col4 * 4 + 2] = v.z;
        sx[r][col4 * 4 + 3] = v.w;
    }
    __syncthreads();

    const int r    = t & 31;
    const int og   = t >> 5;
    const int node = node0 + r;

    float acc[4] = {0.f, 0.f, 0.f, 0.f};
    for (int k = 0; k < IN_CH; ++k) {
        float xv = sx[r][k];
        #pragma unroll
        for (int j = 0; j < 4; ++j)
            acc[j] += xv * sW[k][og * 4 + j];
    }

    if (node < N_NODES) {
        #pragma unroll
        for (int j = 0; j < 4; ++j) {
            int oc = og * 4 + j;
            if (oc < HIDDEN) y1[node * HIDDEN + oc]            = acc[j];
            else             z1[node * HIDDEN + (oc - HIDDEN)] = acc[j];
        }
    }
}

// ---------------------------------------------------------------------------
// Pass B: one block per coarse bucket. Read bucket edges coalesced, place
// srcs into LDS staging rows via LDS atomics, then stream out the 256-node
// row block + true-degree cnt with fully coalesced stores.
// ---------------------------------------------------------------------------
__global__ __launch_bounds__(256) void k_bin(
    const int* __restrict__ gcur, const int* __restrict__ bucket,
    const int2* __restrict__ spill, int* __restrict__ sc,
    uint16_t* __restrict__ row, int* __restrict__ cnt,
    int2* __restrict__ ovf)
{
    __shared__ int cntl[256];
    __shared__ __align__(16) uint16_t stg[256][ROWCAP];   // 24.6 KB
    const int b = blockIdx.x;
    const int t = threadIdx.x;
    cntl[t] = 0;
    __syncthreads();

    const int m = min(gcur[b], BCAP);
    for (int i = t; i < m; i += 256) {
        const int w   = bucket[b * BCAP + i];
        const int nl  = w >> 16;
        const int src = w & 0xFFFF;
        const int pos = atomicAdd(&cntl[nl], 1);          // LDS atomic
        if (pos < ROWCAP) {
            stg[nl][pos] = (uint16_t)src;
        } else {
            const int o = atomicAdd(&sc[1], 1);
            if (o < MAXOVF) ovf[o] = make_int2(b * 256 + nl, src);
        }
    }
    // bucket-overflow spill (length 0 in practice; one cached scalar load)
    const int ns = sc[0];
    if (ns > 0) {
        for (int i = t; i < ns && i < MAXOVF; i += 256) {
            const int2 p = spill[i];
            if ((p.x >> 8) == b) {
                const int nl = p.x & 255;
                const int pos = atomicAdd(&cntl[nl], 1);
                if (pos < ROWCAP) stg[nl][pos] = (uint16_t)p.y;
                else {
                    const int o = atomicAdd(&sc[1], 1);
                    if (o < MAXOVF) ovf[o] = make_int2(p.x, p.y);
                }
            }
        }
    }
    __syncthreads();

    // coalesced stream-out: 256*48*2B = 24576B as 1536 x uint4
    const uint4* s4 = (const uint4*)stg;
    uint4* d4 = (uint4*)(row + (size_t)b * 256 * ROWCAP);
    for (int i = t; i < 1536; i += 256) d4[i] = s4[i];
    cnt[b * 256 + t] = cntl[t];                           // true degree
}

// ---------------------------------------------------------------------------
// Gather layer 1 (node CSR): wave per node, 4 groups of 16 lanes; group g
// sums slots g, g+4, ... (independent loads). h = relu(mean+b1+z1) in place.
// ---------------------------------------------------------------------------
__global__ __launch_bounds__(256) void k_gather_h(
    const int* __restrict__ cnt, const uint16_t* __restrict__ row,
    const int2* __restrict__ ovf, const int* __restrict__ sc,
    const float* __restrict__ y1, float* __restrict__ z1h,
    const float* __restrict__ b1l)
{
    const int lane = threadIdx.x & 63;
    const int wid  = threadIdx.x >> 6;
    const int n = blockIdx.x * 4 + wid;     // 12500 * 4 = exactly 50000
    const int g = lane >> 4;
    const int c = lane & 15;

    const int dgr   = cnt[n];
    const int slots = dgr < ROWCAP ? dgr : ROWCAP;
    const uint16_t* rp = row + (size_t)n * ROWCAP;

    float s = 0.f;
    for (int i = g; i < slots; i += 4)
        s += y1[(int)rp[i] * HIDDEN + c];

    if (dgr > ROWCAP && g == 0) {
        const int on = sc[1];
        for (int o = 0; o < on && o < MAXOVF; ++o) {
            const int2 p = ovf[o];
            if (p.x == n) s += y1[p.y * HIDDEN + c];
        }
    }

    float st = s;
    st += __shfl_xor(st, 16); st += __shfl_xor(st, 32);

    if (g == 0) {
        const float m = st / fmaxf((float)dgr, 1.0f);
        const size_t idx = (size_t)n * HIDDEN + c;
        z1h[idx] = fmaxf(m + b1l[c] + z1h[idx], 0.f);   // in-place z1 -> h
    }
}

// ---------------------------------------------------------------------------
// Fused gather layer 2 + output (node CSR):
//   mean2 via striped independent h-row gathers, then
//   out = log_softmax(mean2 @ W2l + b2l + h @ W2r), lane = out channel.
// ---------------------------------------------------------------------------
__global__ __launch_bounds__(256) void k_out(
    const int* __restrict__ cnt, const uint16_t* __restrict__ row,
    const int2* __restrict__ ovf, const int* __restrict__ sc,
    const float* __restrict__ h,
    const float* __restrict__ W2l, const float* __restrict__ b2l,
    const float* __restrict__ W2r,
    float* __restrict__ out)
{
    __shared__ float sW[HIDDEN][2][OUT_CH];   // 8 KiB
    __shared__ float sm[4][HIDDEN];
    __shared__ float sh[4][HIDDEN];
    const int t = threadIdx.x;
    for (int i = t; i < HIDDEN * OUT_CH; i += 256) {
        int k = i / OUT_CH, c2 = i % OUT_CH;
        sW[k][0][c2] = W2l[i];
        sW[k][1][c2] = W2r[i];
    }

    const int lane = t & 63;
    const int wid  = t >> 6;
    const int n = blockIdx.x * 4 + wid;
    const int g = lane >> 4;
    const int c = lane & 15;

    const int dgr   = cnt[n];
    const int slots = dgr < ROWCAP ? dgr : ROWCAP;
    const uint16_t* rp = row + (size_t)n * ROWCAP;

    float s = 0.f;
    for (int i = g; i < slots; i += 4)
        s += h[(int)rp[i] * HIDDEN + c];

    if (dgr > ROWCAP && g == 0) {
        const int on = sc[1];
        for (int o = 0; o < on && o < MAXOVF; ++o) {
            const int2 p = ovf[o];
            if (p.x == n) s += h[p.y * HIDDEN + c];
        }
    }

    float st = s;
    st += __shfl_xor(st, 16); st += __shfl_xor(st, 32);
    if (g == 0) {
        sm[wid][c] = st / fmaxf((float)dgr, 1.0f);
        sh[wid][c] = h[(size_t)n * HIDDEN + c];
    }
    __syncthreads();

    float acc = b2l[lane];
    #pragma unroll
    for (int k = 0; k < HIDDEN; ++k)
        acc += sm[wid][k] * sW[k][0][lane] + sh[wid][k] * sW[k][1][lane];

    float mx = acc;
    #pragma unroll
    for (int off = 32; off > 0; off >>= 1)
        mx = fmaxf(mx, __shfl_xor(mx, off));
    float ex = expf(acc - mx);
    float sum = ex;
    #pragma unroll
    for (int off = 32; off > 0; off >>= 1)
        sum += __shfl_xor(sum, off);

    out[(size_t)n * OUT_CH + lane] = acc - mx - logf(sum);
}

// ---------------------------------------------------------------------------
extern "C" void kernel_launch(void* const* d_in, const int* in_sizes, int n_in,
                              void* d_out, int out_size, void* d_ws, size_t ws_size,
                              hipStream_t stream)
{
    const float* x   = (const float*)d_in[0];
    const float* W1l = (const float*)d_in[1];
    const float* b1l = (const float*)d_in[2];
    const float* W1r = (const float*)d_in[3];
    const float* W2l = (const float*)d_in[4];
    const float* b2l = (const float*)d_in[5];
    const float* W2r = (const float*)d_in[6];
    const int*   ei  = (const int*)d_in[7];
    float* out = (float*)d_out;

    const size_t NH = (size_t)N_NODES * HIDDEN;           // 800000
    // layout (~18 MB of ~256 MB ws); all segments 16B-aligned
    int*   bucket = (int*)d_ws;                           // [NB*BCAP]   6.4 MB
    float* bufA   = (float*)(bucket + NB * BCAP);         // y1          3.2 MB
    float* bufB   = bufA + NH;                            // z1 -> h     3.2 MB
    int*   cnt    = (int*)(bufB + NH);                    // [NB*256]    0.2 MB
    int*   gcur   = cnt + NB * 256;                       // [256]
    int2*  spill  = (int2*)(gcur + 256);                  // [MAXOVF]    32 KB
    int2*  ovf    = spill + MAXOVF;                       // [MAXOVF]    32 KB
    int*   sc     = (int*)(ovf + MAXOVF);                 // spill_cnt, ovf_cnt, flag, pad
    uint16_t* row = (uint16_t*)(sc + 4);                  // [NB*256*48] 4.8 MB

    k_init<<<1, 256, 0, stream>>>(gcur, sc, ei);

    // fused: linear1 (blocks 0..LB-1)  +  edge partition (blocks LB..LB+PB-1)
    k_build<<<LB + PB, 256, 0, stream>>>(x, W1l, W1r, bufA, bufB, ei,
                                         bucket, gcur, spill, sc);

    // buckets -> per-node CSR rows + true degrees (LDS atomics, coalesced out)
    k_bin<<<NB, 256, 0, stream>>>(gcur, bucket, spill, sc, row, cnt, ovf);

    // h = relu(mean(y1)+b1+z1) in place over bufB
    k_gather_h<<<N_NODES / 4, 256, 0, stream>>>(cnt, row, ovf, sc,
                                                bufA, bufB, b1l);

    // fused gather2 + linear2 + log_softmax
    k_out<<<N_NODES / 4, 256, 0, stream>>>(cnt, row, ovf, sc, bufB,
                                           W2l, b2l, W2r, out);
}

// Round 11
// 104.049 us; speedup vs baseline: 1.4446x; 1.0873x over previous
//
#include <hip/hip_runtime.h>
#include <stdint.h>

#define N_NODES 50000
#define N_EDGES 800000
#define IN_CH 128
#define HIDDEN 16
#define OUT_CH 64
#define ROWCAP 48                        // per-node CSR slots (96B region)
#define MAXOVF 4096
#define NB 196                           // coarse buckets (dst>>8), 256 nodes each
#define BCAP 8192                        // slots per bucket (avg 4082, +64 sigma)

#define LB ((N_NODES + 31) / 32)         // 1563 linear1-role blocks
#define PB ((N_EDGES + 1023) / 1024)     // 782 partition-role blocks (1024 edges each)

// ---------------------------------------------------------------------------
// gcur[]=0, counters=0, int64/int32 detect -- one tiny launch.
// ---------------------------------------------------------------------------
__global__ __launch_bounds__(256) void k_init(
    int* __restrict__ gcur, int* __restrict__ sc, const int* __restrict__ ei)
{
    const int t = threadIdx.x;
    if (t < 256) gcur[t] = 0;
    if (t == 0) {
        sc[0] = 0;          // spill_cnt
        sc[1] = 0;          // ovf_cnt
        int is64 = 1;
        for (int j = 0; j < 64; ++j) {
            if (ei[2 * j + 1] != 0) { is64 = 0; break; }
        }
        sc[2] = is64;       // flag
    }
}

// ---------------------------------------------------------------------------
// Fused: blocks [0,LB) -> y1 = x@W1l, z1 = x@W1r (LDS-tiled);
//        blocks [LB,LB+PB) -> partition 1024 edges into coarse buckets:
//          LDS histogram -> 1 global atomicAdd per BIN (run reservation)
//          -> packed 4B writes in contiguous runs.
// R8 lesson preserved: no random store depends on a per-edge global atomic.
// ---------------------------------------------------------------------------
__global__ __launch_bounds__(256) void k_build(
    const float* __restrict__ x,
    const float* __restrict__ W1l, const float* __restrict__ W1r,
    float* __restrict__ y1, float* __restrict__ z1,
    const int* __restrict__ ei,
    int* __restrict__ bucket, int* __restrict__ gcur,
    int2* __restrict__ spill, int* __restrict__ sc)
{
    __shared__ float sW[IN_CH][33];        // cols 0-15: W1l, 16-31: W1r (+pad)
    __shared__ float sx[32][IN_CH + 1];
    __shared__ int hist[NB], cur[NB], base[NB];
    const int t = threadIdx.x;

    if (blockIdx.x >= LB) {
        // ---- partition role ----
        const int e0 = (blockIdx.x - LB) * 1024;
        for (int i = t; i < NB; i += 256) { hist[i] = 0; cur[i] = 0; }
        __syncthreads();

        const int is64 = sc[2];
        int srcs[4], dsts[4];
        #pragma unroll
        for (int k = 0; k < 4; ++k) {
            const int e = e0 + t + k * 256;
            int src = 0, dst = -1;
            if (e < N_EDGES) {
                if (is64) { src = ei[2 * e]; dst = ei[2 * (N_EDGES + e)]; }
                else      { src = ei[e];     dst = ei[N_EDGES + e]; }
                atomicAdd(&hist[dst >> 8], 1);            // LDS atomic
            }
            srcs[k] = src; dsts[k] = dst;
        }
        __syncthreads();

        for (int i = t; i < NB; i += 256)
            base[i] = (hist[i] > 0) ? atomicAdd(&gcur[i], hist[i]) : 0;
        __syncthreads();

        #pragma unroll
        for (int k = 0; k < 4; ++k) {
            if (dsts[k] >= 0) {
                const int bin = dsts[k] >> 8;
                const int loc = atomicAdd(&cur[bin], 1);   // LDS atomic
                const int pos = base[bin] + loc;
                if (pos < BCAP) {
                    bucket[bin * BCAP + pos] = ((dsts[k] & 255) << 16) | srcs[k];
                } else {                                   // ~impossible
                    const int o = atomicAdd(&sc[0], 1);
                    if (o < MAXOVF) spill[o] = make_int2(dsts[k], srcs[k]);
                }
            }
        }
        return;
    }

    // ---- linear1 role ----
    for (int i = t; i < IN_CH * HIDDEN; i += 256) {
        int k = i / HIDDEN, c = i % HIDDEN;
        sW[k][c]      = W1l[i];
        sW[k][c + 16] = W1r[i];
    }

    const int node0 = blockIdx.x * 32;
    for (int i = t; i < 32 * (IN_CH / 4); i += 256) {
        int r    = i / (IN_CH / 4);
        int col4 = i % (IN_CH / 4);
        int node = node0 + r;
        float4 v = make_float4(0.f, 0.f, 0.f, 0.f);
        if (node < N_NODES)
            v = ((const float4*)x)[node * (IN_CH / 4) + col4];
        sx[r][col4 * 4 + 0] = v.x;
        sx[r][col4 * 4 + 1] = v.y;
        sx[r][col4 * 4 + 2] = v.z;
        sx[r][col4 * 4 + 3] = v.w;
    }
    __syncthreads();

    const int r    = t & 31;
    const int og   = t >> 5;
    const int node = node0 + r;

    float acc[4] = {0.f, 0.f, 0.f, 0.f};
    for (int k = 0; k < IN_CH; ++k) {
        float xv = sx[r][k];
        #pragma unroll
        for (int j = 0; j < 4; ++j)
            acc[j] += xv * sW[k][og * 4 + j];
    }

    if (node < N_NODES) {
        #pragma unroll
        for (int j = 0; j < 4; ++j) {
            int oc = og * 4 + j;
            if (oc < HIDDEN) y1[node * HIDDEN + oc]            = acc[j];
            else             z1[node * HIDDEN + (oc - HIDDEN)] = acc[j];
        }
    }
}

// ---------------------------------------------------------------------------
// Pass B: one block per coarse bucket. Read bucket edges coalesced, place
// srcs into LDS staging rows via LDS atomics, then stream out the 256-node
// row block + true-degree cnt with fully coalesced stores.
// ---------------------------------------------------------------------------
__global__ __launch_bounds__(256) void k_bin(
    const int* __restrict__ gcur, const int* __restrict__ bucket,
    const int2* __restrict__ spill, int* __restrict__ sc,
    uint16_t* __restrict__ row, int* __restrict__ cnt,
    int2* __restrict__ ovf)
{
    __shared__ int cntl[256];
    __shared__ __align__(16) uint16_t stg[256][ROWCAP];   // 24.6 KB
    const int b = blockIdx.x;
    const int t = threadIdx.x;
    cntl[t] = 0;
    __syncthreads();

    const int m = min(gcur[b], BCAP);
    for (int i = t; i < m; i += 256) {
        const int w   = bucket[b * BCAP + i];
        const int nl  = w >> 16;
        const int src = w & 0xFFFF;
        const int pos = atomicAdd(&cntl[nl], 1);          // LDS atomic
        if (pos < ROWCAP) {
            stg[nl][pos] = (uint16_t)src;
        } else {
            const int o = atomicAdd(&sc[1], 1);
            if (o < MAXOVF) ovf[o] = make_int2(b * 256 + nl, src);
        }
    }
    // bucket-overflow spill (length 0 in practice; one cached scalar load)
    const int ns = sc[0];
    if (ns > 0) {
        for (int i = t; i < ns && i < MAXOVF; i += 256) {
            const int2 p = spill[i];
            if ((p.x >> 8) == b) {
                const int nl = p.x & 255;
                const int pos = atomicAdd(&cntl[nl], 1);
                if (pos < ROWCAP) stg[nl][pos] = (uint16_t)p.y;
                else {
                    const int o = atomicAdd(&sc[1], 1);
                    if (o < MAXOVF) ovf[o] = make_int2(p.x, p.y);
                }
            }
        }
    }
    __syncthreads();

    // coalesced stream-out: 256*48*2B = 24576B as 1536 x uint4
    const uint4* s4 = (const uint4*)stg;
    uint4* d4 = (uint4*)(row + (size_t)b * 256 * ROWCAP);
    for (int i = t; i < 1536; i += 256) d4[i] = s4[i];
    cnt[b * 256 + t] = cntl[t];                           // true degree
}

// ---------------------------------------------------------------------------
// Gather layer 1 (node CSR): wave per node, 4 groups of 16 lanes; group g
// sums slots g, g+4, ... via 4-deep ILP batches (4 independent index loads
// -> 4 independent feature-row loads). h = relu(mean+b1+z1) in place.
// ---------------------------------------------------------------------------
__global__ __launch_bounds__(256) void k_gather_h(
    const int* __restrict__ cnt, const uint16_t* __restrict__ row,
    const int2* __restrict__ ovf, const int* __restrict__ sc,
    const float* __restrict__ y1, float* __restrict__ z1h,
    const float* __restrict__ b1l)
{
    const int lane = threadIdx.x & 63;
    const int wid  = threadIdx.x >> 6;
    const int n = blockIdx.x * 4 + wid;     // 12500 * 4 = exactly 50000
    const int g = lane >> 4;
    const int c = lane & 15;

    const int dgr   = cnt[n];
    const int slots = dgr < ROWCAP ? dgr : ROWCAP;
    const uint16_t* rp = row + (size_t)n * ROWCAP;

    float s = 0.f;
    int i = g;
    for (; i + 12 < slots; i += 16) {       // 4 slots per batch, all in flight
        const int j0 = rp[i];
        const int j1 = rp[i + 4];
        const int j2 = rp[i + 8];
        const int j3 = rp[i + 12];
        const float v0 = y1[j0 * HIDDEN + c];
        const float v1 = y1[j1 * HIDDEN + c];
        const float v2 = y1[j2 * HIDDEN + c];
        const float v3 = y1[j3 * HIDDEN + c];
        s += (v0 + v1) + (v2 + v3);
    }
    for (; i < slots; i += 4)
        s += y1[(int)rp[i] * HIDDEN + c];

    if (dgr > ROWCAP && g == 0) {
        const int on = sc[1];
        for (int o = 0; o < on && o < MAXOVF; ++o) {
            const int2 p = ovf[o];
            if (p.x == n) s += y1[p.y * HIDDEN + c];
        }
    }

    float st = s;
    st += __shfl_xor(st, 16); st += __shfl_xor(st, 32);

    if (g == 0) {
        const float m = st / fmaxf((float)dgr, 1.0f);
        const size_t idx = (size_t)n * HIDDEN + c;
        z1h[idx] = fmaxf(m + b1l[c] + z1h[idx], 0.f);   // in-place z1 -> h
    }
}

// ---------------------------------------------------------------------------
// Fused gather layer 2 + output (node CSR):
//   mean2 via 4-deep ILP batched h-row gathers, then
//   out = log_softmax(mean2 @ W2l + b2l + h @ W2r), lane = out channel.
// ---------------------------------------------------------------------------
__global__ __launch_bounds__(256) void k_out(
    const int* __restrict__ cnt, const uint16_t* __restrict__ row,
    const int2* __restrict__ ovf, const int* __restrict__ sc,
    const float* __restrict__ h,
    const float* __restrict__ W2l, const float* __restrict__ b2l,
    const float* __restrict__ W2r,
    float* __restrict__ out)
{
    __shared__ float sW[HIDDEN][2][OUT_CH];   // 8 KiB
    __shared__ float sm[4][HIDDEN];
    __shared__ float sh[4][HIDDEN];
    const int t = threadIdx.x;
    for (int i = t; i < HIDDEN * OUT_CH; i += 256) {
        int k = i / OUT_CH, c2 = i % OUT_CH;
        sW[k][0][c2] = W2l[i];
        sW[k][1][c2] = W2r[i];
    }

    const int lane = t & 63;
    const int wid  = t >> 6;
    const int n = blockIdx.x * 4 + wid;
    const int g = lane >> 4;
    const int c = lane & 15;

    const int dgr   = cnt[n];
    const int slots = dgr < ROWCAP ? dgr : ROWCAP;
    const uint16_t* rp = row + (size_t)n * ROWCAP;
    const float hval = h[(size_t)n * HIDDEN + c];   // own row, issued early

    float s = 0.f;
    int i = g;
    for (; i + 12 < slots; i += 16) {
        const int j0 = rp[i];
        const int j1 = rp[i + 4];
        const int j2 = rp[i + 8];
        const int j3 = rp[i + 12];
        const float v0 = h[j0 * HIDDEN + c];
        const float v1 = h[j1 * HIDDEN + c];
        const float v2 = h[j2 * HIDDEN + c];
        const float v3 = h[j3 * HIDDEN + c];
        s += (v0 + v1) + (v2 + v3);
    }
    for (; i < slots; i += 4)
        s += h[(int)rp[i] * HIDDEN + c];

    if (dgr > ROWCAP && g == 0) {
        const int on = sc[1];
        for (int o = 0; o < on && o < MAXOVF; ++o) {
            const int2 p = ovf[o];
            if (p.x == n) s += h[p.y * HIDDEN + c];
        }
    }

    float st = s;
    st += __shfl_xor(st, 16); st += __shfl_xor(st, 32);
    if (g == 0) {
        sm[wid][c] = st / fmaxf((float)dgr, 1.0f);
        sh[wid][c] = hval;
    }
    __syncthreads();

    float acc = b2l[lane];
    #pragma unroll
    for (int k = 0; k < HIDDEN; ++k)
        acc += sm[wid][k] * sW[k][0][lane] + sh[wid][k] * sW[k][1][lane];

    float mx = acc;
    #pragma unroll
    for (int off = 32; off > 0; off >>= 1)
        mx = fmaxf(mx, __shfl_xor(mx, off));
    float ex = expf(acc - mx);
    float sum = ex;
    #pragma unroll
    for (int off = 32; off > 0; off >>= 1)
        sum += __shfl_xor(sum, off);

    out[(size_t)n * OUT_CH + lane] = acc - mx - logf(sum);
}

// ---------------------------------------------------------------------------
extern "C" void kernel_launch(void* const* d_in, const int* in_sizes, int n_in,
                              void* d_out, int out_size, void* d_ws, size_t ws_size,
                              hipStream_t stream)
{
    const float* x   = (const float*)d_in[0];
    const float* W1l = (const float*)d_in[1];
    const float* b1l = (const float*)d_in[2];
    const float* W1r = (const float*)d_in[3];
    const float* W2l = (const float*)d_in[4];
    const float* b2l = (const float*)d_in[5];
    const float* W2r = (const float*)d_in[6];
    const int*   ei  = (const int*)d_in[7];
    float* out = (float*)d_out;

    const size_t NH = (size_t)N_NODES * HIDDEN;           // 800000
    // layout (~18 MB of ~256 MB ws); all segments 16B-aligned
    int*   bucket = (int*)d_ws;                           // [NB*BCAP]   6.4 MB
    float* bufA   = (float*)(bucket + NB * BCAP);         // y1          3.2 MB
    float* bufB   = bufA + NH;                            // z1 -> h     3.2 MB
    int*   cnt    = (int*)(bufB + NH);                    // [NB*256]    0.2 MB
    int*   gcur   = cnt + NB * 256;                       // [256]
    int2*  spill  = (int2*)(gcur + 256);                  // [MAXOVF]    32 KB
    int2*  ovf    = spill + MAXOVF;                       // [MAXOVF]    32 KB
    int*   sc     = (int*)(ovf + MAXOVF);                 // spill_cnt, ovf_cnt, flag, pad
    uint16_t* row = (uint16_t*)(sc + 4);                  // [NB*256*48] 4.8 MB

    k_init<<<1, 256, 0, stream>>>(gcur, sc, ei);

    // fused: linear1 (blocks 0..LB-1)  +  edge partition (blocks LB..LB+PB-1)
    k_build<<<LB + PB, 256, 0, stream>>>(x, W1l, W1r, bufA, bufB, ei,
                                         bucket, gcur, spill, sc);

    // buckets -> per-node CSR rows + true degrees (LDS atomics, coalesced out)
    k_bin<<<NB, 256, 0, stream>>>(gcur, bucket, spill, sc, row, cnt, ovf);

    // h = relu(mean(y1)+b1+z1) in place over bufB
    k_gather_h<<<N_NODES / 4, 256, 0, stream>>>(cnt, row, ovf, sc,
                                                bufA, bufB, b1l);

    // fused gather2 + linear2 + log_softmax
    k_out<<<N_NODES / 4, 256, 0, stream>>>(cnt, row, ovf, sc, bufB,
                                           W2l, b2l, W2r, out);
}

// Round 13
// 99.102 us; speedup vs baseline: 1.5167x; 1.0499x over previous
//
#include <hip/hip_runtime.h>
#include <stdint.h>

#define N_NODES 50000
#define N_EDGES 800000
#define IN_CH 128
#define HIDDEN 16
#define OUT_CH 64
#define ROWCAP 48                        // per-node CSR slots (96B region)
#define MAXOVF 4096
#define NB 782                           // coarse buckets (dst>>6), 64 nodes each
#define BCAP 1280                        // slots per bucket (avg 1024, +8 sigma)
#define NPAD (NB * 64)                   // 50048 padded node slots

#define LB ((N_NODES + 31) / 32)         // 1563 linear1-role blocks
#define PEB 4096                         // edges per partition block
#define PB ((N_EDGES + PEB - 1) / PEB)   // 196 partition blocks (1024 thr x 4)

// ---------------------------------------------------------------------------
// gcur[NB]=0, counters=0, int64/int32 detect -- one block.
// ---------------------------------------------------------------------------
__global__ __launch_bounds__(1024) void k_init(
    int* __restrict__ gcur, int* __restrict__ sc, const int* __restrict__ ei)
{
    const int t = threadIdx.x;
    if (t < NB) gcur[t] = 0;
    if (t == 0) {
        sc[0] = 0;          // spill_cnt
        sc[1] = 0;          // ovf_cnt
        int is64 = 1;
        for (int j = 0; j < 64; ++j) {
            if (ei[2 * j + 1] != 0) { is64 = 0; break; }
        }
        sc[2] = is64;       // flag
    }
}

// ---------------------------------------------------------------------------
// Partition 4096 edges/block into 782 coarse buckets:
//   LDS histogram -> 1 global atomicAdd per nonempty BIN (run reservation)
//   -> packed 4B writes in contiguous runs.
// R8 lesson: the only per-edge random op is the LDS atomic; global atomics
// are per-bin (~152k total); bucket writes land in short contiguous runs.
// ---------------------------------------------------------------------------
__global__ __launch_bounds__(1024) void k_part(
    const int* __restrict__ ei,
    int* __restrict__ bucket, int* __restrict__ gcur,
    int2* __restrict__ spill, int* __restrict__ sc)
{
    __shared__ int hist[NB], cur[NB], base[NB];
    const int t = threadIdx.x;
    const int e0 = blockIdx.x * PEB;

    if (t < NB) { hist[t] = 0; cur[t] = 0; }
    __syncthreads();

    const int is64 = sc[2];
    int srcs[4], dsts[4];
    #pragma unroll
    for (int k = 0; k < 4; ++k) {
        const int e = e0 + t + k * 1024;
        int src = 0, dst = -1;
        if (e < N_EDGES) {
            if (is64) {
                src = ((const int2*)ei)[e].x;              // 8B coalesced
                dst = ((const int2*)ei)[N_EDGES + e].x;
            } else {
                src = ei[e];
                dst = ei[N_EDGES + e];
            }
            atomicAdd(&hist[dst >> 6], 1);                 // LDS atomic
        }
        srcs[k] = src; dsts[k] = dst;
    }
    __syncthreads();

    if (t < NB)
        base[t] = (hist[t] > 0) ? atomicAdd(&gcur[t], hist[t]) : 0;
    __syncthreads();

    #pragma unroll
    for (int k = 0; k < 4; ++k) {
        if (dsts[k] >= 0) {
            const int bin = dsts[k] >> 6;
            const int loc = atomicAdd(&cur[bin], 1);       // LDS atomic
            const int pos = base[bin] + loc;
            if (pos < BCAP) {
                bucket[bin * BCAP + pos] = ((dsts[k] & 63) << 16) | srcs[k];
            } else {                                       // ~impossible
                const int o = atomicAdd(&sc[0], 1);
                if (o < MAXOVF) spill[o] = make_int2(dsts[k], srcs[k]);
            }
        }
    }
}

// ---------------------------------------------------------------------------
// Fused: blocks [0,NB) -> bin role: bucket -> per-node CSR rows via LDS
//        atomics (64-node staging), coalesced stream-out + true-degree cnt.
//        blocks [NB,NB+LB) -> linear1: y1 = x@W1l, z1 = x@W1r (LDS-tiled).
// Bin blocks are dispatched FIRST so the latency-bound binning overlaps the
// compute-bound linear1 across CUs. Bin role aliases linear1's LDS.
// ---------------------------------------------------------------------------
__global__ __launch_bounds__(256) void k_mid(
    const float* __restrict__ x,
    const float* __restrict__ W1l, const float* __restrict__ W1r,
    float* __restrict__ y1, float* __restrict__ z1,
    const int* __restrict__ gcur, const int* __restrict__ bucket,
    const int2* __restrict__ spill, int* __restrict__ sc,
    uint16_t* __restrict__ row, int* __restrict__ cnt,
    int2* __restrict__ ovf)
{
    __shared__ float sW[IN_CH][33];        // cols 0-15: W1l, 16-31: W1r (+pad)
    __shared__ float sx[32][IN_CH + 1];
    const int t = threadIdx.x;

    if (blockIdx.x < NB) {
        // ---- bin role (aliases sW as staging, sx as counters) ----
        uint16_t* stg = (uint16_t*)&sW[0][0];     // [64][ROWCAP] = 6 KB
        int* cntl     = (int*)&sx[0][0];          // [64]
        const int b = blockIdx.x;
        if (t < 64) cntl[t] = 0;
        __syncthreads();

        const int m = min(gcur[b], BCAP);
        for (int i = t; i < m; i += 256) {
            const int w   = bucket[b * BCAP + i];
            const int nl  = (w >> 16) & 63;
            const int src = w & 0xFFFF;
            const int pos = atomicAdd(&cntl[nl], 1);       // LDS atomic
            if (pos < ROWCAP) {
                stg[nl * ROWCAP + pos] = (uint16_t)src;
            } else {
                const int o = atomicAdd(&sc[1], 1);
                if (o < MAXOVF) ovf[o] = make_int2(b * 64 + nl, src);
            }
        }
        const int ns = sc[0];                     // bucket spill (0 in practice)
        if (ns > 0) {
            for (int i = t; i < ns && i < MAXOVF; i += 256) {
                const int2 p = spill[i];
                if ((p.x >> 6) == b) {
                    const int nl = p.x & 63;
                    const int pos = atomicAdd(&cntl[nl], 1);
                    if (pos < ROWCAP) stg[nl * ROWCAP + pos] = (uint16_t)p.y;
                    else {
                        const int o = atomicAdd(&sc[1], 1);
                        if (o < MAXOVF) ovf[o] = make_int2(p.x, p.y);
                    }
                }
            }
        }
        __syncthreads();

        // coalesced stream-out: 64*48*2B = 6144B as 384 x uint4
        // (R12 bug: `if (t < 384)` with a 256-thread block dropped slots
        //  256..383 -> ~1/3 of nodes got stale rows. Strided loop fixes it.)
        const uint4* s4 = (const uint4*)stg;
        uint4* d4 = (uint4*)(row + (size_t)b * 64 * ROWCAP);
        for (int i = t; i < 384; i += 256) d4[i] = s4[i];
        if (t < 64) cnt[b * 64 + t] = cntl[t];             // true degree
        return;
    }

    // ---- linear1 role ----
    for (int i = t; i < IN_CH * HIDDEN; i += 256) {
        int k = i / HIDDEN, c = i % HIDDEN;
        sW[k][c]      = W1l[i];
        sW[k][c + 16] = W1r[i];
    }

    const int node0 = (blockIdx.x - NB) * 32;
    for (int i = t; i < 32 * (IN_CH / 4); i += 256) {
        int r    = i / (IN_CH / 4);
        int col4 = i % (IN_CH / 4);
        int node = node0 + r;
        float4 v = make_float4(0.f, 0.f, 0.f, 0.f);
        if (node < N_NODES)
            v = ((const float4*)x)[node * (IN_CH / 4) + col4];
        sx[r][col4 * 4 + 0] = v.x;
        sx[r][col4 * 4 + 1] = v.y;
        sx[r][col4 * 4 + 2] = v.z;
        sx[r][col4 * 4 + 3] = v.w;
    }
    __syncthreads();

    const int r    = t & 31;
    const int og   = t >> 5;
    const int node = node0 + r;

    float acc[4] = {0.f, 0.f, 0.f, 0.f};
    for (int k = 0; k < IN_CH; ++k) {
        float xv = sx[r][k];
        #pragma unroll
        for (int j = 0; j < 4; ++j)
            acc[j] += xv * sW[k][og * 4 + j];
    }

    if (node < N_NODES) {
        #pragma unroll
        for (int j = 0; j < 4; ++j) {
            int oc = og * 4 + j;
            if (oc < HIDDEN) y1[node * HIDDEN + oc]            = acc[j];
            else             z1[node * HIDDEN + (oc - HIDDEN)] = acc[j];
        }
    }
}

// ---------------------------------------------------------------------------
// Gather layer 1 (node CSR): wave per node, 4 groups of 16 lanes; group g
// sums slots g, g+4, ... via 4-deep ILP batches. h = relu(mean+b1+z1).
// ---------------------------------------------------------------------------
__global__ __launch_bounds__(256) void k_gather_h(
    const int* __restrict__ cnt, const uint16_t* __restrict__ row,
    const int2* __restrict__ ovf, const int* __restrict__ sc,
    const float* __restrict__ y1, float* __restrict__ z1h,
    const float* __restrict__ b1l)
{
    const int lane = threadIdx.x & 63;
    const int wid  = threadIdx.x >> 6;
    const int n = blockIdx.x * 4 + wid;     // 12500 * 4 = exactly 50000
    const int g = lane >> 4;
    const int c = lane & 15;

    const int dgr   = cnt[n];
    const int slots = dgr < ROWCAP ? dgr : ROWCAP;
    const uint16_t* rp = row + (size_t)n * ROWCAP;

    float s = 0.f;
    int i = g;
    for (; i + 12 < slots; i += 16) {       // 4 slots per batch, all in flight
        const int j0 = rp[i];
        const int j1 = rp[i + 4];
        const int j2 = rp[i + 8];
        const int j3 = rp[i + 12];
        const float v0 = y1[j0 * HIDDEN + c];
        const float v1 = y1[j1 * HIDDEN + c];
        const float v2 = y1[j2 * HIDDEN + c];
        const float v3 = y1[j3 * HIDDEN + c];
        s += (v0 + v1) + (v2 + v3);
    }
    for (; i < slots; i += 4)
        s += y1[(int)rp[i] * HIDDEN + c];

    if (dgr > ROWCAP && g == 0) {
        const int on = sc[1];
        for (int o = 0; o < on && o < MAXOVF; ++o) {
            const int2 p = ovf[o];
            if (p.x == n) s += y1[p.y * HIDDEN + c];
        }
    }

    float st = s;
    st += __shfl_xor(st, 16); st += __shfl_xor(st, 32);

    if (g == 0) {
        const float m = st / fmaxf((float)dgr, 1.0f);
        const size_t idx = (size_t)n * HIDDEN + c;
        z1h[idx] = fmaxf(m + b1l[c] + z1h[idx], 0.f);   // in-place z1 -> h
    }
}

// ---------------------------------------------------------------------------
// Fused gather layer 2 + output (node CSR):
//   mean2 via 4-deep ILP batched h-row gathers, then
//   out = log_softmax(mean2 @ W2l + b2l + h @ W2r), lane = out channel.
// ---------------------------------------------------------------------------
__global__ __launch_bounds__(256) void k_out(
    const int* __restrict__ cnt, const uint16_t* __restrict__ row,
    const int2* __restrict__ ovf, const int* __restrict__ sc,
    const float* __restrict__ h,
    const float* __restrict__ W2l, const float* __restrict__ b2l,
    const float* __restrict__ W2r,
    float* __restrict__ out)
{
    __shared__ float sW[HIDDEN][2][OUT_CH];   // 8 KiB
    __shared__ float sm[4][HIDDEN];
    __shared__ float sh[4][HIDDEN];
    const int t = threadIdx.x;
    for (int i = t; i < HIDDEN * OUT_CH; i += 256) {
        int k = i / OUT_CH, c2 = i % OUT_CH;
        sW[k][0][c2] = W2l[i];
        sW[k][1][c2] = W2r[i];
    }

    const int lane = t & 63;
    const int wid  = t >> 6;
    const int n = blockIdx.x * 4 + wid;
    const int g = lane >> 4;
    const int c = lane & 15;

    const int dgr   = cnt[n];
    const int slots = dgr < ROWCAP ? dgr : ROWCAP;
    const uint16_t* rp = row + (size_t)n * ROWCAP;
    const float hval = h[(size_t)n * HIDDEN + c];   // own row, issued early

    float s = 0.f;
    int i = g;
    for (; i + 12 < slots; i += 16) {
        const int j0 = rp[i];
        const int j1 = rp[i + 4];
        const int j2 = rp[i + 8];
        const int j3 = rp[i + 12];
        const float v0 = h[j0 * HIDDEN + c];
        const float v1 = h[j1 * HIDDEN + c];
        const float v2 = h[j2 * HIDDEN + c];
        const float v3 = h[j3 * HIDDEN + c];
        s += (v0 + v1) + (v2 + v3);
    }
    for (; i < slots; i += 4)
        s += h[(int)rp[i] * HIDDEN + c];

    if (dgr > ROWCAP && g == 0) {
        const int on = sc[1];
        for (int o = 0; o < on && o < MAXOVF; ++o) {
            const int2 p = ovf[o];
            if (p.x == n) s += h[p.y * HIDDEN + c];
        }
    }

    float st = s;
    st += __shfl_xor(st, 16); st += __shfl_xor(st, 32);
    if (g == 0) {
        sm[wid][c] = st / fmaxf((float)dgr, 1.0f);
        sh[wid][c] = hval;
    }
    __syncthreads();

    float acc = b2l[lane];
    #pragma unroll
    for (int k = 0; k < HIDDEN; ++k)
        acc += sm[wid][k] * sW[k][0][lane] + sh[wid][k] * sW[k][1][lane];

    float mx = acc;
    #pragma unroll
    for (int off = 32; off > 0; off >>= 1)
        mx = fmaxf(mx, __shfl_xor(mx, off));
    float ex = expf(acc - mx);
    float sum = ex;
    #pragma unroll
    for (int off = 32; off > 0; off >>= 1)
        sum += __shfl_xor(sum, off);

    out[(size_t)n * OUT_CH + lane] = acc - mx - logf(sum);
}

// ---------------------------------------------------------------------------
extern "C" void kernel_launch(void* const* d_in, const int* in_sizes, int n_in,
                              void* d_out, int out_size, void* d_ws, size_t ws_size,
                              hipStream_t stream)
{
    const float* x   = (const float*)d_in[0];
    const float* W1l = (const float*)d_in[1];
    const float* b1l = (const float*)d_in[2];
    const float* W1r = (const float*)d_in[3];
    const float* W2l = (const float*)d_in[4];
    const float* b2l = (const float*)d_in[5];
    const float* W2r = (const float*)d_in[6];
    const int*   ei  = (const int*)d_in[7];
    float* out = (float*)d_out;

    const size_t NH = (size_t)N_NODES * HIDDEN;           // 800000
    // layout (~16 MB of ~256 MB ws); all segments 16B-aligned
    int*   bucket = (int*)d_ws;                           // [NB*BCAP]   4.0 MB
    float* bufA   = (float*)(bucket + NB * BCAP);         // y1          3.2 MB
    float* bufB   = bufA + NH;                            // z1 -> h     3.2 MB
    int*   cnt    = (int*)(bufB + NH);                    // [NPAD]      0.2 MB
    int*   gcur   = cnt + NPAD;                           // [NB]
    int2*  spill  = (int2*)(gcur + NB + 2);               // [MAXOVF]    32 KB
    int2*  ovf    = spill + MAXOVF;                       // [MAXOVF]    32 KB
    int*   sc     = (int*)(ovf + MAXOVF);                 // spill_cnt, ovf_cnt, flag, pad
    uint16_t* row = (uint16_t*)(sc + 4);                  // [NPAD*48]   4.8 MB

    k_init<<<1, 1024, 0, stream>>>(gcur, sc, ei);

    // edge partition into 782 coarse buckets (196 blocks x 1024 thr)
    k_part<<<PB, 1024, 0, stream>>>(ei, bucket, gcur, spill, sc);

    // fused: bin role (blocks 0..NB-1, dispatched first) + linear1 role
    k_mid<<<NB + LB, 256, 0, stream>>>(x, W1l, W1r, bufA, bufB,
                                       gcur, bucket, spill, sc, row, cnt, ovf);

    // h = relu(mean(y1)+b1+z1) in place over bufB
    k_gather_h<<<N_NODES / 4, 256, 0, stream>>>(cnt, row, ovf, sc,
                                                bufA, bufB, b1l);

    // fused gather2 + linear2 + log_softmax
    k_out<<<N_NODES / 4, 256, 0, stream>>>(cnt, row, ovf, sc, bufB,
                                           W2l, b2l, W2r, out);
}

// Round 14
// 98.042 us; speedup vs baseline: 1.5331x; 1.0108x over previous
//
#include <hip/hip_runtime.h>
#include <stdint.h>

#define N_NODES 50000
#define N_EDGES 800000
#define IN_CH 128
#define HIDDEN 16
#define OUT_CH 64
#define ROWCAP 48                        // per-node CSR slots (96B region)
#define MAXOVF 4096
#define NB 782                           // coarse buckets (dst>>6), 64 nodes each
#define BCAP 1280                        // slots per bucket (avg 1024, +8 sigma)
#define NPAD (NB * 64)                   // 50048 padded node slots

#define LB ((N_NODES + 31) / 32)         // 1563 linear1-role blocks
#define PEB 2048                         // edges per partition block
#define PB ((N_EDGES + PEB - 1) / PEB)   // 391 partition blocks (1024 thr x 2)

// ---------------------------------------------------------------------------
// gcur[NB]=0, counters=0, int64/int32 detect -- one block.
// ---------------------------------------------------------------------------
__global__ __launch_bounds__(1024) void k_init(
    int* __restrict__ gcur, int* __restrict__ sc, const int* __restrict__ ei)
{
    const int t = threadIdx.x;
    if (t < NB) gcur[t] = 0;
    if (t == 0) {
        sc[0] = 0;          // spill_cnt
        sc[1] = 0;          // ovf_cnt
        int is64 = 1;
        for (int j = 0; j < 64; ++j) {
            if (ei[2 * j + 1] != 0) { is64 = 0; break; }
        }
        sc[2] = is64;       // flag
    }
}

// ---------------------------------------------------------------------------
// Partition 2048 edges/block into 782 coarse buckets:
//   LDS histogram -> 1 global atomicAdd per nonempty BIN (run reservation)
//   -> packed 4B writes in contiguous runs.
// R8 lesson: the only per-edge random op is the LDS atomic; global atomics
// are per-bin (~300k total); bucket writes land in short contiguous runs.
// ---------------------------------------------------------------------------
__global__ __launch_bounds__(1024) void k_part(
    const int* __restrict__ ei,
    int* __restrict__ bucket, int* __restrict__ gcur,
    int2* __restrict__ spill, int* __restrict__ sc)
{
    __shared__ int hist[NB], cur[NB], base[NB];
    const int t = threadIdx.x;
    const int e0 = blockIdx.x * PEB;

    if (t < NB) { hist[t] = 0; cur[t] = 0; }
    __syncthreads();

    const int is64 = sc[2];
    int srcs[2], dsts[2];
    #pragma unroll
    for (int k = 0; k < 2; ++k) {
        const int e = e0 + t + k * 1024;
        int src = 0, dst = -1;
        if (e < N_EDGES) {
            if (is64) {
                src = ((const int2*)ei)[e].x;              // 8B coalesced
                dst = ((const int2*)ei)[N_EDGES + e].x;
            } else {
                src = ei[e];
                dst = ei[N_EDGES + e];
            }
            atomicAdd(&hist[dst >> 6], 1);                 // LDS atomic
        }
        srcs[k] = src; dsts[k] = dst;
    }
    __syncthreads();

    if (t < NB)
        base[t] = (hist[t] > 0) ? atomicAdd(&gcur[t], hist[t]) : 0;
    __syncthreads();

    #pragma unroll
    for (int k = 0; k < 2; ++k) {
        if (dsts[k] >= 0) {
            const int bin = dsts[k] >> 6;
            const int loc = atomicAdd(&cur[bin], 1);       // LDS atomic
            const int pos = base[bin] + loc;
            if (pos < BCAP) {
                bucket[bin * BCAP + pos] = ((dsts[k] & 63) << 16) | srcs[k];
            } else {                                       // ~impossible
                const int o = atomicAdd(&sc[0], 1);
                if (o < MAXOVF) spill[o] = make_int2(dsts[k], srcs[k]);
            }
        }
    }
}

// ---------------------------------------------------------------------------
// Fused: blocks [0,NB) -> bin role: bucket -> per-node CSR rows via LDS
//        atomics (64-node staging), coalesced stream-out + true-degree cnt.
//        blocks [NB,NB+LB) -> linear1: y1 = x@W1l, z1 = x@W1r (LDS-tiled).
// Bin blocks dispatched FIRST so latency-bound binning overlaps compute-bound
// linear1 across CUs. Bin role aliases linear1's LDS.
// linear1 inner loop: sW padded to 36 -> 16B-aligned float4 weight reads
// (one ds_read_b128 broadcast replaces 4 scalar reads).
// ---------------------------------------------------------------------------
__global__ __launch_bounds__(256) void k_mid(
    const float* __restrict__ x,
    const float* __restrict__ W1l, const float* __restrict__ W1r,
    float* __restrict__ y1, float* __restrict__ z1,
    const int* __restrict__ gcur, const int* __restrict__ bucket,
    const int2* __restrict__ spill, int* __restrict__ sc,
    uint16_t* __restrict__ row, int* __restrict__ cnt,
    int2* __restrict__ ovf)
{
    __shared__ float sW[IN_CH][36];        // cols 0-15: W1l, 16-31: W1r; 36 keeps
                                           // &sW[k][og*4] 16B-aligned, bank-clean
    __shared__ float sx[32][IN_CH + 1];
    const int t = threadIdx.x;

    if (blockIdx.x < NB) {
        // ---- bin role (aliases sW as staging, sx as counters) ----
        uint16_t* stg = (uint16_t*)&sW[0][0];     // [64][ROWCAP] = 6 KB
        int* cntl     = (int*)&sx[0][0];          // [64]
        const int b = blockIdx.x;
        if (t < 64) cntl[t] = 0;
        __syncthreads();

        const int m = min(gcur[b], BCAP);
        for (int i = t; i < m; i += 256) {
            const int w   = bucket[b * BCAP + i];
            const int nl  = (w >> 16) & 63;
            const int src = w & 0xFFFF;
            const int pos = atomicAdd(&cntl[nl], 1);       // LDS atomic
            if (pos < ROWCAP) {
                stg[nl * ROWCAP + pos] = (uint16_t)src;
            } else {
                const int o = atomicAdd(&sc[1], 1);
                if (o < MAXOVF) ovf[o] = make_int2(b * 64 + nl, src);
            }
        }
        const int ns = sc[0];                     // bucket spill (0 in practice)
        if (ns > 0) {
            for (int i = t; i < ns && i < MAXOVF; i += 256) {
                const int2 p = spill[i];
                if ((p.x >> 6) == b) {
                    const int nl = p.x & 63;
                    const int pos = atomicAdd(&cntl[nl], 1);
                    if (pos < ROWCAP) stg[nl * ROWCAP + pos] = (uint16_t)p.y;
                    else {
                        const int o = atomicAdd(&sc[1], 1);
                        if (o < MAXOVF) ovf[o] = make_int2(p.x, p.y);
                    }
                }
            }
        }
        __syncthreads();

        // coalesced stream-out: 64*48*2B = 6144B as 384 x uint4 (strided loop!)
        const uint4* s4 = (const uint4*)stg;
        uint4* d4 = (uint4*)(row + (size_t)b * 64 * ROWCAP);
        for (int i = t; i < 384; i += 256) d4[i] = s4[i];
        if (t < 64) cnt[b * 64 + t] = cntl[t];             // true degree
        return;
    }

    // ---- linear1 role ----
    for (int i = t; i < IN_CH * HIDDEN; i += 256) {
        int k = i / HIDDEN, c = i % HIDDEN;
        sW[k][c]      = W1l[i];
        sW[k][c + 16] = W1r[i];
    }

    const int node0 = (blockIdx.x - NB) * 32;
    for (int i = t; i < 32 * (IN_CH / 4); i += 256) {
        int r    = i / (IN_CH / 4);
        int col4 = i % (IN_CH / 4);
        int node = node0 + r;
        float4 v = make_float4(0.f, 0.f, 0.f, 0.f);
        if (node < N_NODES)
            v = ((const float4*)x)[node * (IN_CH / 4) + col4];
        sx[r][col4 * 4 + 0] = v.x;
        sx[r][col4 * 4 + 1] = v.y;
        sx[r][col4 * 4 + 2] = v.z;
        sx[r][col4 * 4 + 3] = v.w;
    }
    __syncthreads();

    const int r    = t & 31;
    const int og   = t >> 5;
    const int node = node0 + r;

    float4 acc = make_float4(0.f, 0.f, 0.f, 0.f);
    #pragma unroll 4
    for (int k = 0; k < IN_CH; ++k) {
        const float xv = sx[r][k];
        const float4 w4 = *(const float4*)&sW[k][og * 4];  // ds_read_b128 bcast
        acc.x += xv * w4.x;
        acc.y += xv * w4.y;
        acc.z += xv * w4.z;
        acc.w += xv * w4.w;
    }

    if (node < N_NODES) {
        const int oc = og * 4;
        float vals[4] = {acc.x, acc.y, acc.z, acc.w};
        #pragma unroll
        for (int j = 0; j < 4; ++j) {
            int o = oc + j;
            if (o < HIDDEN) y1[node * HIDDEN + o]            = vals[j];
            else            z1[node * HIDDEN + (o - HIDDEN)] = vals[j];
        }
    }
}

// ---------------------------------------------------------------------------
// Gather layer 1 (node CSR): wave per node, 4 groups of 16 lanes; group g
// sums slots g, g+4, ... via 4-deep ILP batches. h = relu(mean+b1+z1).
// ---------------------------------------------------------------------------
__global__ __launch_bounds__(256) void k_gather_h(
    const int* __restrict__ cnt, const uint16_t* __restrict__ row,
    const int2* __restrict__ ovf, const int* __restrict__ sc,
    const float* __restrict__ y1, float* __restrict__ z1h,
    const float* __restrict__ b1l)
{
    const int lane = threadIdx.x & 63;
    const int wid  = threadIdx.x >> 6;
    const int n = blockIdx.x * 4 + wid;     // 12500 * 4 = exactly 50000
    const int g = lane >> 4;
    const int c = lane & 15;

    const int dgr   = cnt[n];
    const int slots = dgr < ROWCAP ? dgr : ROWCAP;
    const uint16_t* rp = row + (size_t)n * ROWCAP;

    float s = 0.f;
    int i = g;
    for (; i + 12 < slots; i += 16) {       // 4 slots per batch, all in flight
        const int j0 = rp[i];
        const int j1 = rp[i + 4];
        const int j2 = rp[i + 8];
        const int j3 = rp[i + 12];
        const float v0 = y1[j0 * HIDDEN + c];
        const float v1 = y1[j1 * HIDDEN + c];
        const float v2 = y1[j2 * HIDDEN + c];
        const float v3 = y1[j3 * HIDDEN + c];
        s += (v0 + v1) + (v2 + v3);
    }
    for (; i < slots; i += 4)
        s += y1[(int)rp[i] * HIDDEN + c];

    if (dgr > ROWCAP && g == 0) {
        const int on = sc[1];
        for (int o = 0; o < on && o < MAXOVF; ++o) {
            const int2 p = ovf[o];
            if (p.x == n) s += y1[p.y * HIDDEN + c];
        }
    }

    float st = s;
    st += __shfl_xor(st, 16); st += __shfl_xor(st, 32);

    if (g == 0) {
        const float m = st / fmaxf((float)dgr, 1.0f);
        const size_t idx = (size_t)n * HIDDEN + c;
        z1h[idx] = fmaxf(m + b1l[c] + z1h[idx], 0.f);   // in-place z1 -> h
    }
}

// ---------------------------------------------------------------------------
// Fused gather layer 2 + output (node CSR), 16 nodes/block (1024 thr):
//   gather loads issued FIRST (latency-critical chain), weight staging after
//   (independent, overlaps), then matmul + log_softmax; lane = out channel.
// ---------------------------------------------------------------------------
__global__ __launch_bounds__(1024) void k_out(
    const int* __restrict__ cnt, const uint16_t* __restrict__ row,
    const int2* __restrict__ ovf, const int* __restrict__ sc,
    const float* __restrict__ h,
    const float* __restrict__ W2l, const float* __restrict__ b2l,
    const float* __restrict__ W2r,
    float* __restrict__ out)
{
    __shared__ float sW[HIDDEN][2][OUT_CH];   // 8 KiB
    __shared__ float sm[16][HIDDEN];
    __shared__ float sh[16][HIDDEN];
    const int t = threadIdx.x;

    const int lane = t & 63;
    const int wid  = t >> 6;                  // 0..15
    const int n = blockIdx.x * 16 + wid;      // 3125 * 16 = exactly 50000
    const int g = lane >> 4;
    const int c = lane & 15;

    // ---- gather phase first: start the index->feature chain immediately ----
    const int dgr   = cnt[n];
    const int slots = dgr < ROWCAP ? dgr : ROWCAP;
    const uint16_t* rp = row + (size_t)n * ROWCAP;
    const float hval = h[(size_t)n * HIDDEN + c];

    float s = 0.f;
    int i = g;
    for (; i + 12 < slots; i += 16) {
        const int j0 = rp[i];
        const int j1 = rp[i + 4];
        const int j2 = rp[i + 8];
        const int j3 = rp[i + 12];
        const float v0 = h[j0 * HIDDEN + c];
        const float v1 = h[j1 * HIDDEN + c];
        const float v2 = h[j2 * HIDDEN + c];
        const float v3 = h[j3 * HIDDEN + c];
        s += (v0 + v1) + (v2 + v3);
    }
    for (; i < slots; i += 4)
        s += h[(int)rp[i] * HIDDEN + c];

    if (dgr > ROWCAP && g == 0) {
        const int on = sc[1];
        for (int o = 0; o < on && o < MAXOVF; ++o) {
            const int2 p = ovf[o];
            if (p.x == n) s += h[p.y * HIDDEN + c];
        }
    }

    float st = s;
    st += __shfl_xor(st, 16); st += __shfl_xor(st, 32);
    if (g == 0) {
        sm[wid][c] = st / fmaxf((float)dgr, 1.0f);
        sh[wid][c] = hval;
    }

    // ---- weight staging (independent of gather; single strided pass) ----
    for (int i2 = t; i2 < HIDDEN * OUT_CH; i2 += 1024) {
        int k = i2 / OUT_CH, c2 = i2 % OUT_CH;
        sW[k][0][c2] = W2l[i2];
        sW[k][1][c2] = W2r[i2];
    }
    __syncthreads();

    float acc = b2l[lane];
    #pragma unroll
    for (int k = 0; k < HIDDEN; ++k)
        acc += sm[wid][k] * sW[k][0][lane] + sh[wid][k] * sW[k][1][lane];

    float mx = acc;
    #pragma unroll
    for (int off = 32; off > 0; off >>= 1)
        mx = fmaxf(mx, __shfl_xor(mx, off));
    float ex = expf(acc - mx);
    float sum = ex;
    #pragma unroll
    for (int off = 32; off > 0; off >>= 1)
        sum += __shfl_xor(sum, off);

    out[(size_t)n * OUT_CH + lane] = acc - mx - logf(sum);
}

// ---------------------------------------------------------------------------
extern "C" void kernel_launch(void* const* d_in, const int* in_sizes, int n_in,
                              void* d_out, int out_size, void* d_ws, size_t ws_size,
                              hipStream_t stream)
{
    const float* x   = (const float*)d_in[0];
    const float* W1l = (const float*)d_in[1];
    const float* b1l = (const float*)d_in[2];
    const float* W1r = (const float*)d_in[3];
    const float* W2l = (const float*)d_in[4];
    const float* b2l = (const float*)d_in[5];
    const float* W2r = (const float*)d_in[6];
    const int*   ei  = (const int*)d_in[7];
    float* out = (float*)d_out;

    const size_t NH = (size_t)N_NODES * HIDDEN;           // 800000
    // layout (~16 MB of ~256 MB ws); all segments 16B-aligned
    int*   bucket = (int*)d_ws;                           // [NB*BCAP]   4.0 MB
    float* bufA   = (float*)(bucket + NB * BCAP);         // y1          3.2 MB
    float* bufB   = bufA + NH;                            // z1 -> h     3.2 MB
    int*   cnt    = (int*)(bufB + NH);                    // [NPAD]      0.2 MB
    int*   gcur   = cnt + NPAD;                           // [NB]
    int2*  spill  = (int2*)(gcur + NB + 2);               // [MAXOVF]    32 KB
    int2*  ovf    = spill + MAXOVF;                       // [MAXOVF]    32 KB
    int*   sc     = (int*)(ovf + MAXOVF);                 // spill_cnt, ovf_cnt, flag, pad
    uint16_t* row = (uint16_t*)(sc + 4);                  // [NPAD*48]   4.8 MB

    k_init<<<1, 1024, 0, stream>>>(gcur, sc, ei);

    // edge partition into 782 coarse buckets (391 blocks x 1024 thr x 2)
    k_part<<<PB, 1024, 0, stream>>>(ei, bucket, gcur, spill, sc);

    // fused: bin role (blocks 0..NB-1, dispatched first) + linear1 role
    k_mid<<<NB + LB, 256, 0, stream>>>(x, W1l, W1r, bufA, bufB,
                                       gcur, bucket, spill, sc, row, cnt, ovf);

    // h = relu(mean(y1)+b1+z1) in place over bufB
    k_gather_h<<<N_NODES / 4, 256, 0, stream>>>(cnt, row, ovf, sc,
                                                bufA, bufB, b1l);

    // fused gather2 + linear2 + log_softmax (16 nodes/block)
    k_out<<<N_NODES / 16, 1024, 0, stream>>>(cnt, row, ovf, sc, bufB,
                                             W2l, b2l, W2r, out);
}

// Round 15
// 90.105 us; speedup vs baseline: 1.6681x; 1.0881x over previous
//
#include <hip/hip_runtime.h>
#include <stdint.h>

#define N_NODES 50000
#define N_EDGES 800000
#define IN_CH 128
#define HIDDEN 16
#define OUT_CH 64
#define ROWCAP 48                        // per-node CSR slots (96B region)
#define NBB 782                          // buckets (dst>>6), 64 nodes each
#define NPAD (NBB * 64)                  // 50048 padded node slots
#define OVFCAP 64                        // per-bucket overflow slots

#define LB ((N_NODES + 31) / 32)         // 1563 linear1-role blocks
#define PEB 2048                         // edges per partition block
#define PB ((N_EDGES + PEB - 1) / PEB)   // 391 partition blocks

// ---------------------------------------------------------------------------
// Owner-computes partition: each block counting-sorts its 2048 edges into its
// OWN bucket region (fully coalesced) + writes a base-offset row (uint16).
// Zero global atomics; is64 self-detected per block (one ballot round).
// ---------------------------------------------------------------------------
__global__ __launch_bounds__(1024) void k_part(
    const int* __restrict__ ei,
    int* __restrict__ bucket,            // [PB * PEB]
    uint16_t* __restrict__ base16)       // [PB * 784]
{
    __shared__ int hist[1024];
    __shared__ int cur[1024];
    __shared__ __align__(16) int stg[PEB];
    __shared__ int lflag;
    const int t = threadIdx.x;
    const int blk = blockIdx.x;
    const int e0 = blk * PEB;

    // parallel int64/int32 detect (values < 50000 -> odd words all 0 if int64)
    if (t < 64) {
        const int v = ei[2 * t + 1];
        const unsigned long long b = __ballot(v != 0);
        if (t == 0) lflag = (b == 0ull);
    }
    hist[t] = 0;
    __syncthreads();
    const int is64 = lflag;

    int srcs[2], dsts[2];
    #pragma unroll
    for (int k = 0; k < 2; ++k) {
        const int e = e0 + t + k * 1024;
        int src = 0, dst = -1;
        if (e < N_EDGES) {
            if (is64) {
                src = ((const int2*)ei)[e].x;              // 8B coalesced
                dst = ((const int2*)ei)[N_EDGES + e].x;
            } else {
                src = ei[e];
                dst = ei[N_EDGES + e];
            }
            atomicAdd(&hist[dst >> 6], 1);                 // LDS atomic
        }
        srcs[k] = src; dsts[k] = dst;
    }
    __syncthreads();

    const int mycnt = hist[t];            // save own count before scan
    __syncthreads();

    // Hillis-Steele inclusive scan over 1024 slots (bins 782..1023 are 0)
    for (int off = 1; off < 1024; off <<= 1) {
        const int v = (t >= off) ? hist[t - off] : 0;
        __syncthreads();
        hist[t] += v;
        __syncthreads();
    }
    const int mybase = hist[t] - mycnt;   // exclusive prefix
    cur[t] = mybase;
    __syncthreads();

    #pragma unroll
    for (int k = 0; k < 2; ++k) {
        if (dsts[k] >= 0) {
            const int bin = dsts[k] >> 6;
            const int pos = atomicAdd(&cur[bin], 1);       // LDS atomic
            stg[pos] = ((dsts[k] & 63) << 16) | srcs[k];
        }
    }
    __syncthreads();

    // coalesced stream-out: 2048 ints as 1024 x int2
    ((int2*)(bucket + (size_t)blk * PEB))[t] = ((const int2*)stg)[t];
    // base row: [0..781]=bases, [782..783]=total (sentinel)
    if (t < 784) base16[blk * 784 + t] = (uint16_t)mybase;
}

// ---------------------------------------------------------------------------
// Fused: blocks [0,NBB) -> bin role: gather this bucket's runs from all 391
//        part regions, place into 64-node LDS staging via LDS atomics,
//        stream out rows + true-degree cnt + bucket-owned overflow (no
//        global atomics: this block is the bucket's sole owner).
//        blocks [NBB,NBB+LB) -> linear1: y1 = x@W1l, z1 = x@W1r (LDS-tiled,
//        float4 ds_read_b128 weight broadcasts).
// ---------------------------------------------------------------------------
__global__ __launch_bounds__(256) void k_mid(
    const float* __restrict__ x,
    const float* __restrict__ W1l, const float* __restrict__ W1r,
    float* __restrict__ y1, float* __restrict__ z1,
    const int* __restrict__ bucket, const uint16_t* __restrict__ base16,
    uint16_t* __restrict__ row, int* __restrict__ cnt,
    int* __restrict__ govf, int* __restrict__ ovfcnt)
{
    __shared__ float sW[IN_CH][36];        // 36: keeps &sW[k][og*4] 16B-aligned
    __shared__ float sx[32][IN_CH + 1];
    const int t = threadIdx.x;

    if (blockIdx.x < NBB) {
        // ---- bin role (aliases sW as staging, sx as counters) ----
        uint16_t* stg = (uint16_t*)&sW[0][0];     // [64][ROWCAP] = 6 KB
        int* cntl     = (int*)&sx[0][0];          // [64]
        int* ovfc     = cntl + 64;
        const int b = blockIdx.x;
        if (t < 64) cntl[t] = 0;
        if (t == 64) *ovfc = 0;
        __syncthreads();

        for (int pb = t; pb < PB; pb += 256) {
            const int lo = base16[pb * 784 + b];
            const int hi = base16[pb * 784 + b + 1];
            const int* bp = bucket + (size_t)pb * PEB;
            for (int i = lo; i < hi; ++i) {
                const int w   = bp[i];
                const int nl  = (w >> 16) & 63;
                const int src = w & 0xFFFF;
                const int pos = atomicAdd(&cntl[nl], 1);   // LDS atomic
                if (pos < ROWCAP) {
                    stg[nl * ROWCAP + pos] = (uint16_t)src;
                } else {
                    const int o = atomicAdd(ovfc, 1);      // LDS atomic
                    if (o < OVFCAP) govf[b * OVFCAP + o] = w;
                }
            }
        }
        __syncthreads();

        // coalesced stream-out: 64*48*2B = 6144B as 384 x uint4 (strided!)
        const uint4* s4 = (const uint4*)stg;
        uint4* d4 = (uint4*)(row + (size_t)b * 64 * ROWCAP);
        for (int i = t; i < 384; i += 256) d4[i] = s4[i];
        if (t < 64) cnt[b * 64 + t] = cntl[t];             // true degree
        if (t == 64) ovfcnt[b] = min(*ovfc, OVFCAP);
        return;
    }

    // ---- linear1 role ----
    for (int i = t; i < IN_CH * HIDDEN; i += 256) {
        int k = i / HIDDEN, c = i % HIDDEN;
        sW[k][c]      = W1l[i];
        sW[k][c + 16] = W1r[i];
    }

    const int node0 = (blockIdx.x - NBB) * 32;
    for (int i = t; i < 32 * (IN_CH / 4); i += 256) {
        int r    = i / (IN_CH / 4);
        int col4 = i % (IN_CH / 4);
        int node = node0 + r;
        float4 v = make_float4(0.f, 0.f, 0.f, 0.f);
        if (node < N_NODES)
            v = ((const float4*)x)[node * (IN_CH / 4) + col4];
        sx[r][col4 * 4 + 0] = v.x;
        sx[r][col4 * 4 + 1] = v.y;
        sx[r][col4 * 4 + 2] = v.z;
        sx[r][col4 * 4 + 3] = v.w;
    }
    __syncthreads();

    const int r    = t & 31;
    const int og   = t >> 5;
    const int node = node0 + r;

    float4 acc = make_float4(0.f, 0.f, 0.f, 0.f);
    #pragma unroll 4
    for (int k = 0; k < IN_CH; ++k) {
        const float xv = sx[r][k];
        const float4 w4 = *(const float4*)&sW[k][og * 4];  // ds_read_b128
        acc.x += xv * w4.x;
        acc.y += xv * w4.y;
        acc.z += xv * w4.z;
        acc.w += xv * w4.w;
    }

    if (node < N_NODES) {
        const int oc = og * 4;
        float vals[4] = {acc.x, acc.y, acc.z, acc.w};
        #pragma unroll
        for (int j = 0; j < 4; ++j) {
            int o = oc + j;
            if (o < HIDDEN) y1[node * HIDDEN + o]            = vals[j];
            else            z1[node * HIDDEN + (o - HIDDEN)] = vals[j];
        }
    }
}

// ---------------------------------------------------------------------------
// Gather layer 1 (node CSR): 16 nodes/block (1024 thr), wave per node,
// 4 groups of 16 lanes, 4-deep ILP batches. h = relu(mean+b1+z1) in place.
// ---------------------------------------------------------------------------
__global__ __launch_bounds__(1024) void k_gather_h(
    const int* __restrict__ cnt, const uint16_t* __restrict__ row,
    const int* __restrict__ govf, const int* __restrict__ ovfcnt,
    const float* __restrict__ y1, float* __restrict__ z1h,
    const float* __restrict__ b1l)
{
    const int t = threadIdx.x;
    const int lane = t & 63;
    const int wid  = t >> 6;
    const int n = blockIdx.x * 16 + wid;    // 3125 * 16 = exactly 50000
    const int g = lane >> 4;
    const int c = lane & 15;

    const int dgr   = cnt[n];
    const int slots = dgr < ROWCAP ? dgr : ROWCAP;
    const uint16_t* rp = row + (size_t)n * ROWCAP;

    float s = 0.f;
    int i = g;
    for (; i + 12 < slots; i += 16) {       // 4 slots in flight
        const int j0 = rp[i];
        const int j1 = rp[i + 4];
        const int j2 = rp[i + 8];
        const int j3 = rp[i + 12];
        const float v0 = y1[j0 * HIDDEN + c];
        const float v1 = y1[j1 * HIDDEN + c];
        const float v2 = y1[j2 * HIDDEN + c];
        const float v3 = y1[j3 * HIDDEN + c];
        s += (v0 + v1) + (v2 + v3);
    }
    for (; i < slots; i += 4)
        s += y1[(int)rp[i] * HIDDEN + c];

    if (dgr > ROWCAP && g == 0) {           // bucket-owned overflow scan
        const int b = n >> 6;
        const int on = ovfcnt[b];
        for (int o = 0; o < on; ++o) {
            const int w = govf[b * OVFCAP + o];
            if (((w >> 16) & 63) == (n & 63)) s += y1[(w & 0xFFFF) * HIDDEN + c];
        }
    }

    float st = s;
    st += __shfl_xor(st, 16); st += __shfl_xor(st, 32);

    if (g == 0) {
        const float m = st / fmaxf((float)dgr, 1.0f);
        const size_t idx = (size_t)n * HIDDEN + c;
        z1h[idx] = fmaxf(m + b1l[c] + z1h[idx], 0.f);   // in-place z1 -> h
    }
}

// ---------------------------------------------------------------------------
// Fused gather layer 2 + output, 16 nodes/block (1024 thr): gather first
// (latency chain starts at wave launch), weight staging overlaps, then
// matmul + log_softmax; lane = out channel.
// ---------------------------------------------------------------------------
__global__ __launch_bounds__(1024) void k_out(
    const int* __restrict__ cnt, const uint16_t* __restrict__ row,
    const int* __restrict__ govf, const int* __restrict__ ovfcnt,
    const float* __restrict__ h,
    const float* __restrict__ W2l, const float* __restrict__ b2l,
    const float* __restrict__ W2r,
    float* __restrict__ out)
{
    __shared__ float sW[HIDDEN][2][OUT_CH];   // 8 KiB
    __shared__ float sm[16][HIDDEN];
    __shared__ float sh[16][HIDDEN];
    const int t = threadIdx.x;

    const int lane = t & 63;
    const int wid  = t >> 6;                  // 0..15
    const int n = blockIdx.x * 16 + wid;      // 3125 * 16 = exactly 50000
    const int g = lane >> 4;
    const int c = lane & 15;

    const int dgr   = cnt[n];
    const int slots = dgr < ROWCAP ? dgr : ROWCAP;
    const uint16_t* rp = row + (size_t)n * ROWCAP;
    const float hval = h[(size_t)n * HIDDEN + c];

    float s = 0.f;
    int i = g;
    for (; i + 12 < slots; i += 16) {
        const int j0 = rp[i];
        const int j1 = rp[i + 4];
        const int j2 = rp[i + 8];
        const int j3 = rp[i + 12];
        const float v0 = h[j0 * HIDDEN + c];
        const float v1 = h[j1 * HIDDEN + c];
        const float v2 = h[j2 * HIDDEN + c];
        const float v3 = h[j3 * HIDDEN + c];
        s += (v0 + v1) + (v2 + v3);
    }
    for (; i < slots; i += 4)
        s += h[(int)rp[i] * HIDDEN + c];

    if (dgr > ROWCAP && g == 0) {
        const int b = n >> 6;
        const int on = ovfcnt[b];
        for (int o = 0; o < on; ++o) {
            const int w = govf[b * OVFCAP + o];
            if (((w >> 16) & 63) == (n & 63)) s += h[(w & 0xFFFF) * HIDDEN + c];
        }
    }

    float st = s;
    st += __shfl_xor(st, 16); st += __shfl_xor(st, 32);
    if (g == 0) {
        sm[wid][c] = st / fmaxf((float)dgr, 1.0f);
        sh[wid][c] = hval;
    }

    // weight staging (independent of gather; one element per thread)
    {
        const int k = t / OUT_CH, c2 = t % OUT_CH;
        sW[k][0][c2] = W2l[t];
        sW[k][1][c2] = W2r[t];
    }
    __syncthreads();

    float acc = b2l[lane];
    #pragma unroll
    for (int k = 0; k < HIDDEN; ++k)
        acc += sm[wid][k] * sW[k][0][lane] + sh[wid][k] * sW[k][1][lane];

    float mx = acc;
    #pragma unroll
    for (int off = 32; off > 0; off >>= 1)
        mx = fmaxf(mx, __shfl_xor(mx, off));
    float ex = expf(acc - mx);
    float sum = ex;
    #pragma unroll
    for (int off = 32; off > 0; off >>= 1)
        sum += __shfl_xor(sum, off);

    out[(size_t)n * OUT_CH + lane] = acc - mx - logf(sum);
}

// ---------------------------------------------------------------------------
extern "C" void kernel_launch(void* const* d_in, const int* in_sizes, int n_in,
                              void* d_out, int out_size, void* d_ws, size_t ws_size,
                              hipStream_t stream)
{
    const float* x   = (const float*)d_in[0];
    const float* W1l = (const float*)d_in[1];
    const float* b1l = (const float*)d_in[2];
    const float* W1r = (const float*)d_in[3];
    const float* W2l = (const float*)d_in[4];
    const float* b2l = (const float*)d_in[5];
    const float* W2r = (const float*)d_in[6];
    const int*   ei  = (const int*)d_in[7];
    float* out = (float*)d_out;

    const size_t NH = (size_t)N_NODES * HIDDEN;           // 800000
    // layout (~16 MB of ~256 MB ws); 4B-aligned segments first, then 2B
    int*   bucket = (int*)d_ws;                           // [PB*PEB]    3.2 MB
    float* bufA   = (float*)(bucket + PB * PEB);          // y1          3.2 MB
    float* bufB   = bufA + NH;                            // z1 -> h     3.2 MB
    int*   cnt    = (int*)(bufB + NH);                    // [NPAD]      0.2 MB
    int*   govf   = cnt + NPAD;                           // [NBB*64]    0.2 MB
    int*   ovfcnt = govf + NBB * OVFCAP;                  // [NBB]
    uint16_t* base16 = (uint16_t*)(ovfcnt + NBB + 2);     // [PB*784]    0.61 MB
    uint16_t* row    = base16 + (size_t)PB * 784;         // [NPAD*48]   4.8 MB

    // owner-computes partition: counting sort, zero global atomics, no init
    k_part<<<PB, 1024, 0, stream>>>(ei, bucket, base16);

    // fused: bin role (blocks 0..NBB-1) + linear1 role
    k_mid<<<NBB + LB, 256, 0, stream>>>(x, W1l, W1r, bufA, bufB,
                                        bucket, base16, row, cnt, govf, ovfcnt);

    // h = relu(mean(y1)+b1+z1) in place over bufB
    k_gather_h<<<N_NODES / 16, 1024, 0, stream>>>(cnt, row, govf, ovfcnt,
                                                  bufA, bufB, b1l);

    // fused gather2 + linear2 + log_softmax
    k_out<<<N_NODES / 16, 1024, 0, stream>>>(cnt, row, govf, ovfcnt, bufB,
                                             W2l, b2l, W2r, out);
}

// Round 16
// 86.990 us; speedup vs baseline: 1.7279x; 1.0358x over previous
//
#include <hip/hip_runtime.h>
#include <stdint.h>

#define N_NODES 50000
#define N_EDGES 800000
#define IN_CH 128
#define HIDDEN 16
#define OUT_CH 64
#define ROWCAP 48                        // per-node CSR slots (96B region)
#define NBB 782                          // buckets (dst>>6), 64 nodes each
#define NPAD (NBB * 64)                  // 50048 padded node slots
#define OVFCAP 64                        // per-bucket overflow slots

#define LB ((N_NODES + 31) / 32)         // 1563 linear1-role blocks
#define PEB 2048                         // edges per partition block
#define PB ((N_EDGES + PEB - 1) / PEB)   // 391 partition blocks

// ---------------------------------------------------------------------------
// Owner-computes partition: each block counting-sorts its 2048 edges into its
// OWN bucket region (fully coalesced) + writes a base-offset row (uint16).
// Zero global atomics; is64 self-detected per block (one ballot round).
// ---------------------------------------------------------------------------
__global__ __launch_bounds__(1024) void k_part(
    const int* __restrict__ ei,
    int* __restrict__ bucket,            // [PB * PEB]
    uint16_t* __restrict__ base16)       // [PB * 784]
{
    __shared__ int hist[1024];
    __shared__ int cur[1024];
    __shared__ __align__(16) int stg[PEB];
    __shared__ int lflag;
    const int t = threadIdx.x;
    const int blk = blockIdx.x;
    const int e0 = blk * PEB;

    if (t < 64) {
        const int v = ei[2 * t + 1];
        const unsigned long long b = __ballot(v != 0);
        if (t == 0) lflag = (b == 0ull);
    }
    hist[t] = 0;
    __syncthreads();
    const int is64 = lflag;

    int srcs[2], dsts[2];
    #pragma unroll
    for (int k = 0; k < 2; ++k) {
        const int e = e0 + t + k * 1024;
        int src = 0, dst = -1;
        if (e < N_EDGES) {
            if (is64) {
                src = ((const int2*)ei)[e].x;              // 8B coalesced
                dst = ((const int2*)ei)[N_EDGES + e].x;
            } else {
                src = ei[e];
                dst = ei[N_EDGES + e];
            }
            atomicAdd(&hist[dst >> 6], 1);                 // LDS atomic
        }
        srcs[k] = src; dsts[k] = dst;
    }
    __syncthreads();

    const int mycnt = hist[t];
    __syncthreads();

    for (int off = 1; off < 1024; off <<= 1) {
        const int v = (t >= off) ? hist[t - off] : 0;
        __syncthreads();
        hist[t] += v;
        __syncthreads();
    }
    const int mybase = hist[t] - mycnt;
    cur[t] = mybase;
    __syncthreads();

    #pragma unroll
    for (int k = 0; k < 2; ++k) {
        if (dsts[k] >= 0) {
            const int bin = dsts[k] >> 6;
            const int pos = atomicAdd(&cur[bin], 1);       // LDS atomic
            stg[pos] = ((dsts[k] & 63) << 16) | srcs[k];
        }
    }
    __syncthreads();

    ((int2*)(bucket + (size_t)blk * PEB))[t] = ((const int2*)stg)[t];
    if (t < 784) base16[blk * 784 + t] = (uint16_t)mybase;
}

// ---------------------------------------------------------------------------
// Fused: blocks [0,NBB) -> bin role; blocks [NBB,NBB+LB) -> linear1.
// (unchanged from R15)
// ---------------------------------------------------------------------------
__global__ __launch_bounds__(256) void k_mid(
    const float* __restrict__ x,
    const float* __restrict__ W1l, const float* __restrict__ W1r,
    float* __restrict__ y1, float* __restrict__ z1,
    const int* __restrict__ bucket, const uint16_t* __restrict__ base16,
    uint16_t* __restrict__ row, int* __restrict__ cnt,
    int* __restrict__ govf, int* __restrict__ ovfcnt)
{
    __shared__ float sW[IN_CH][36];
    __shared__ float sx[32][IN_CH + 1];
    const int t = threadIdx.x;

    if (blockIdx.x < NBB) {
        uint16_t* stg = (uint16_t*)&sW[0][0];     // [64][ROWCAP] = 6 KB
        int* cntl     = (int*)&sx[0][0];          // [64]
        int* ovfc     = cntl + 64;
        const int b = blockIdx.x;
        if (t < 64) cntl[t] = 0;
        if (t == 64) *ovfc = 0;
        __syncthreads();

        for (int pb = t; pb < PB; pb += 256) {
            const int lo = base16[pb * 784 + b];
            const int hi = base16[pb * 784 + b + 1];
            const int* bp = bucket + (size_t)pb * PEB;
            for (int i = lo; i < hi; ++i) {
                const int w   = bp[i];
                const int nl  = (w >> 16) & 63;
                const int src = w & 0xFFFF;
                const int pos = atomicAdd(&cntl[nl], 1);   // LDS atomic
                if (pos < ROWCAP) {
                    stg[nl * ROWCAP + pos] = (uint16_t)src;
                } else {
                    const int o = atomicAdd(ovfc, 1);
                    if (o < OVFCAP) govf[b * OVFCAP + o] = w;
                }
            }
        }
        __syncthreads();

        const uint4* s4 = (const uint4*)stg;
        uint4* d4 = (uint4*)(row + (size_t)b * 64 * ROWCAP);
        for (int i = t; i < 384; i += 256) d4[i] = s4[i];
        if (t < 64) cnt[b * 64 + t] = cntl[t];
        if (t == 64) ovfcnt[b] = min(*ovfc, OVFCAP);
        return;
    }

    // ---- linear1 role ----
    for (int i = t; i < IN_CH * HIDDEN; i += 256) {
        int k = i / HIDDEN, c = i % HIDDEN;
        sW[k][c]      = W1l[i];
        sW[k][c + 16] = W1r[i];
    }

    const int node0 = (blockIdx.x - NBB) * 32;
    for (int i = t; i < 32 * (IN_CH / 4); i += 256) {
        int r    = i / (IN_CH / 4);
        int col4 = i % (IN_CH / 4);
        int node = node0 + r;
        float4 v = make_float4(0.f, 0.f, 0.f, 0.f);
        if (node < N_NODES)
            v = ((const float4*)x)[node * (IN_CH / 4) + col4];
        sx[r][col4 * 4 + 0] = v.x;
        sx[r][col4 * 4 + 1] = v.y;
        sx[r][col4 * 4 + 2] = v.z;
        sx[r][col4 * 4 + 3] = v.w;
    }
    __syncthreads();

    const int r    = t & 31;
    const int og   = t >> 5;
    const int node = node0 + r;

    float4 acc = make_float4(0.f, 0.f, 0.f, 0.f);
    #pragma unroll 4
    for (int k = 0; k < IN_CH; ++k) {
        const float xv = sx[r][k];
        const float4 w4 = *(const float4*)&sW[k][og * 4];  // ds_read_b128
        acc.x += xv * w4.x;
        acc.y += xv * w4.y;
        acc.z += xv * w4.z;
        acc.w += xv * w4.w;
    }

    if (node < N_NODES) {
        const int oc = og * 4;
        float vals[4] = {acc.x, acc.y, acc.z, acc.w};
        #pragma unroll
        for (int j = 0; j < 4; ++j) {
            int o = oc + j;
            if (o < HIDDEN) y1[node * HIDDEN + o]            = vals[j];
            else            z1[node * HIDDEN + (o - HIDDEN)] = vals[j];
        }
    }
}

// ---------------------------------------------------------------------------
// float4-quartered gather core (shared idea of k_gather_h / k_out):
// one WAVE per node; lane l handles quarter q=l&3 of row i+(l>>2) -> one wave
// instruction covers 16 rows; butterfly shfl_xor{4,8,16,32} reduces the 16
// row-partials per quarter. Two-step pipelining covers deg<=32 (99.99%).
// ---------------------------------------------------------------------------
__device__ __forceinline__ float4 gather_rows_f4(
    const float* __restrict__ feat, const uint16_t* __restrict__ rp,
    int slots, int ri, int q)
{
    float4 s = make_float4(0.f, 0.f, 0.f, 0.f);
    int i = 0;
    while (i + 16 < slots) {               // step0 full, step1 predicated
        const int j0 = rp[i + ri];
        const int idx1 = i + 16 + ri;
        const bool p1 = idx1 < slots;
        const int j1 = p1 ? rp[idx1] : 0;
        const float4 v0 = ((const float4*)(feat + j0 * HIDDEN))[q];
        float4 v1 = make_float4(0.f, 0.f, 0.f, 0.f);
        if (p1) v1 = ((const float4*)(feat + j1 * HIDDEN))[q];
        s.x += v0.x + v1.x; s.y += v0.y + v1.y;
        s.z += v0.z + v1.z; s.w += v0.w + v1.w;
        i += 32;
    }
    if (i + ri < slots) {
        const int j = rp[i + ri];
        const float4 v = ((const float4*)(feat + j * HIDDEN))[q];
        s.x += v.x; s.y += v.y; s.z += v.z; s.w += v.w;
    }
    // butterfly over ri (bits 2..5 of lane): all lanes end with quarter totals
    #pragma unroll
    for (int off = 4; off <= 32; off <<= 1) {
        s.x += __shfl_xor(s.x, off);
        s.y += __shfl_xor(s.y, off);
        s.z += __shfl_xor(s.z, off);
        s.w += __shfl_xor(s.w, off);
    }
    return s;
}

// ---------------------------------------------------------------------------
// Gather layer 1: 16 nodes/block (1024 thr), one wave per node, float4 core.
// h = relu(mean + b1 + z1) in place over z1 (float4 by lanes 0-3).
// ---------------------------------------------------------------------------
__global__ __launch_bounds__(1024) void k_gather_h(
    const int* __restrict__ cnt, const uint16_t* __restrict__ row,
    const int* __restrict__ govf, const int* __restrict__ ovfcnt,
    const float* __restrict__ y1, float* __restrict__ z1h,
    const float* __restrict__ b1l)
{
    const int t = threadIdx.x;
    const int lane = t & 63;
    const int wid  = t >> 6;
    const int n = blockIdx.x * 16 + wid;    // 3125 * 16 = exactly 50000
    const int q  = lane & 3;
    const int ri = lane >> 2;

    const int dgr   = cnt[n];
    const int slots = dgr < ROWCAP ? dgr : ROWCAP;
    const uint16_t* rp = row + (size_t)n * ROWCAP;

    float4 s = gather_rows_f4(y1, rp, slots, ri, q);

    if (dgr > ROWCAP) {                     // rare; all lanes mirror totals
        const int b = n >> 6;
        const int on = ovfcnt[b];
        for (int o = 0; o < on; ++o) {
            const int w = govf[b * OVFCAP + o];
            if (((w >> 16) & 63) == (n & 63)) {
                const float4 v = ((const float4*)(y1 + (w & 0xFFFF) * HIDDEN))[q];
                s.x += v.x; s.y += v.y; s.z += v.z; s.w += v.w;
            }
        }
    }

    if (lane < 4) {
        const float inv = 1.0f / fmaxf((float)dgr, 1.0f);
        const float4 b4 = ((const float4*)b1l)[q];
        float4* zp = (float4*)(z1h + (size_t)n * HIDDEN) + q;
        const float4 z4 = *zp;
        float4 hv;
        hv.x = fmaxf(s.x * inv + b4.x + z4.x, 0.f);
        hv.y = fmaxf(s.y * inv + b4.y + z4.y, 0.f);
        hv.z = fmaxf(s.z * inv + b4.z + z4.z, 0.f);
        hv.w = fmaxf(s.w * inv + b4.w + z4.w, 0.f);
        *zp = hv;                           // in-place z1 -> h
    }
}

// ---------------------------------------------------------------------------
// Fused gather layer 2 + output: 16 nodes/block (1024 thr), float4 gather
// first (latency chain starts at launch), weight staging overlaps, then
// matmul + log_softmax; lane = out channel.
// ---------------------------------------------------------------------------
__global__ __launch_bounds__(1024) void k_out(
    const int* __restrict__ cnt, const uint16_t* __restrict__ row,
    const int* __restrict__ govf, const int* __restrict__ ovfcnt,
    const float* __restrict__ h,
    const float* __restrict__ W2l, const float* __restrict__ b2l,
    const float* __restrict__ W2r,
    float* __restrict__ out)
{
    __shared__ float sW[HIDDEN][2][OUT_CH];   // 8 KiB
    __shared__ float sm[16][HIDDEN];
    __shared__ float sh[16][HIDDEN];
    const int t = threadIdx.x;

    const int lane = t & 63;
    const int wid  = t >> 6;
    const int n = blockIdx.x * 16 + wid;      // 3125 * 16 = exactly 50000
    const int q  = lane & 3;
    const int ri = lane >> 2;

    const int dgr   = cnt[n];
    const int slots = dgr < ROWCAP ? dgr : ROWCAP;
    const uint16_t* rp = row + (size_t)n * ROWCAP;

    float4 s = gather_rows_f4(h, rp, slots, ri, q);

    if (dgr > ROWCAP) {
        const int b = n >> 6;
        const int on = ovfcnt[b];
        for (int o = 0; o < on; ++o) {
            const int w = govf[b * OVFCAP + o];
            if (((w >> 16) & 63) == (n & 63)) {
                const float4 v = ((const float4*)(h + (w & 0xFFFF) * HIDDEN))[q];
                s.x += v.x; s.y += v.y; s.z += v.z; s.w += v.w;
            }
        }
    }

    if (lane < 4) {
        const float inv = 1.0f / fmaxf((float)dgr, 1.0f);
        float4 m4;
        m4.x = s.x * inv; m4.y = s.y * inv; m4.z = s.z * inv; m4.w = s.w * inv;
        ((float4*)&sm[wid][0])[q] = m4;
        ((float4*)&sh[wid][0])[q] = ((const float4*)(h + (size_t)n * HIDDEN))[q];
    }

    // weight staging (independent of gather; one element per thread)
    {
        const int k = t / OUT_CH, c2 = t % OUT_CH;
        sW[k][0][c2] = W2l[t];
        sW[k][1][c2] = W2r[t];
    }
    __syncthreads();

    float acc = b2l[lane];
    #pragma unroll
    for (int k = 0; k < HIDDEN; ++k)
        acc += sm[wid][k] * sW[k][0][lane] + sh[wid][k] * sW[k][1][lane];

    float mx = acc;
    #pragma unroll
    for (int off = 32; off > 0; off >>= 1)
        mx = fmaxf(mx, __shfl_xor(mx, off));
    float ex = expf(acc - mx);
    float sum = ex;
    #pragma unroll
    for (int off = 32; off > 0; off >>= 1)
        sum += __shfl_xor(sum, off);

    out[(size_t)n * OUT_CH + lane] = acc - mx - logf(sum);
}

// ---------------------------------------------------------------------------
extern "C" void kernel_launch(void* const* d_in, const int* in_sizes, int n_in,
                              void* d_out, int out_size, void* d_ws, size_t ws_size,
                              hipStream_t stream)
{
    const float* x   = (const float*)d_in[0];
    const float* W1l = (const float*)d_in[1];
    const float* b1l = (const float*)d_in[2];
    const float* W1r = (const float*)d_in[3];
    const float* W2l = (const float*)d_in[4];
    const float* b2l = (const float*)d_in[5];
    const float* W2r = (const float*)d_in[6];
    const int*   ei  = (const int*)d_in[7];
    float* out = (float*)d_out;

    const size_t NH = (size_t)N_NODES * HIDDEN;           // 800000
    int*   bucket = (int*)d_ws;                           // [PB*PEB]    3.2 MB
    float* bufA   = (float*)(bucket + PB * PEB);          // y1          3.2 MB
    float* bufB   = bufA + NH;                            // z1 -> h     3.2 MB
    int*   cnt    = (int*)(bufB + NH);                    // [NPAD]      0.2 MB
    int*   govf   = cnt + NPAD;                           // [NBB*64]    0.2 MB
    int*   ovfcnt = govf + NBB * OVFCAP;                  // [NBB]
    uint16_t* base16 = (uint16_t*)(ovfcnt + NBB + 2);     // [PB*784]    0.61 MB
    uint16_t* row    = base16 + (size_t)PB * 784;         // [NPAD*48]   4.8 MB

    // owner-computes partition: counting sort, zero global atomics, no init
    k_part<<<PB, 1024, 0, stream>>>(ei, bucket, base16);

    // fused: bin role (blocks 0..NBB-1) + linear1 role
    k_mid<<<NBB + LB, 256, 0, stream>>>(x, W1l, W1r, bufA, bufB,
                                        bucket, base16, row, cnt, govf, ovfcnt);

    // h = relu(mean(y1)+b1+z1) in place over bufB
    k_gather_h<<<N_NODES / 16, 1024, 0, stream>>>(cnt, row, govf, ovfcnt,
                                                  bufA, bufB, b1l);

    // fused gather2 + linear2 + log_softmax
    k_out<<<N_NODES / 16, 1024, 0, stream>>>(cnt, row, govf, ovfcnt, bufB,
                                             W2l, b2l, W2r, out);
}

// Round 17
// 78.615 us; speedup vs baseline: 1.9120x; 1.1065x over previous
//
#include <hip/hip_runtime.h>
#include <stdint.h>

#define N_NODES 50000
#define N_EDGES 800000
#define IN_CH 128
#define HIDDEN 16
#define OUT_CH 64
#define ROWCAP 48                        // per-node CSR slots (96B region)
#define NBB 782                          // buckets (dst>>6), 64 nodes each
#define NPAD (NBB * 64)                  // 50048 padded node slots
#define OVFCAP 64                        // per-bucket overflow slots

#define PEB 1024                         // edges per partition block
#define PB ((N_EDGES + PEB - 1) / PEB)   // 782 partition blocks (256 thr x 4)
#define LB ((N_NODES + 31) / 32)         // 1563 linear1-role blocks

// ---------------------------------------------------------------------------
// K1: blocks [0,PB) -> owner-computes partition (256 thr, counting sort of
//     1024 edges into 782 bins; zero global atomics; coalesced stream-out).
//     blocks [PB,PB+LB) -> linear1: y1 = x@W1l, z1 = x@W1r (LDS-tiled).
// The two roles have no data dependency -> overlap across CUs.
// ---------------------------------------------------------------------------
__global__ __launch_bounds__(256) void k_front(
    const int* __restrict__ ei,
    int* __restrict__ bucket,            // [PB * PEB]
    uint16_t* __restrict__ base16,       // [PB * 784]
    const float* __restrict__ x,
    const float* __restrict__ W1l, const float* __restrict__ W1r,
    float* __restrict__ y1, float* __restrict__ z1)
{
    __shared__ float sW[IN_CH][36];        // linear1 weights (aliased by part)
    __shared__ float sx[32][IN_CH + 1];    // linear1 x tile  (aliased by part)
    const int t = threadIdx.x;

    if (blockIdx.x < PB) {
        // ---- partition role (aliases: stg->sW, hist/cur/wsum/flag->sx) ----
        int* stg  = (int*)&sW[0][0];               // [1024] 4 KB
        int* hist = (int*)&sx[0][0];               // [784]
        int* cur  = hist + 784;                    // [784]
        int* wsum = cur + 784;                     // [4]
        int* lflag = wsum + 4;
        const int blk = blockIdx.x;
        const int e0 = blk * PEB;
        const int lane = t & 63;
        const int wid  = t >> 6;

        if (t < 64) {
            const int v = ei[2 * t + 1];
            const unsigned long long b = __ballot(v != 0);
            if (t == 0) *lflag = (b == 0ull);
        }
        for (int i = t; i < 784; i += 256) hist[i] = 0;
        __syncthreads();
        const int is64 = *lflag;

        int srcs[4], dsts[4];
        #pragma unroll
        for (int k = 0; k < 4; ++k) {
            const int e = e0 + t + k * 256;
            int src = 0, dst = -1;
            if (e < N_EDGES) {
                if (is64) {
                    src = ((const int2*)ei)[e].x;          // 8B coalesced
                    dst = ((const int2*)ei)[N_EDGES + e].x;
                } else {
                    src = ei[e];
                    dst = ei[N_EDGES + e];
                }
                atomicAdd(&hist[dst >> 6], 1);             // LDS atomic
            }
            srcs[k] = src; dsts[k] = dst;
        }
        __syncthreads();

        // hierarchical exclusive scan: 4 bins/thread + wave shfl + wsum scan
        int tot = 0;
        #pragma unroll
        for (int j = 0; j < 4; ++j) {
            const int idx = 4 * t + j;
            if (idx < 784) tot += hist[idx];
        }
        int inc = tot;
        #pragma unroll
        for (int off = 1; off < 64; off <<= 1) {
            const int u = __shfl_up(inc, off);
            if (lane >= off) inc += u;
        }
        if (lane == 63) wsum[wid] = inc;
        __syncthreads();
        if (t == 0) {
            int run = 0;
            #pragma unroll
            for (int w = 0; w < 4; ++w) { const int v = wsum[w]; wsum[w] = run; run += v; }
        }
        __syncthreads();
        int run = inc - tot + wsum[wid];       // exclusive prefix of my chunk
        #pragma unroll
        for (int j = 0; j < 4; ++j) {
            const int idx = 4 * t + j;
            if (idx < 784) {
                cur[idx] = run;
                base16[blk * 784 + idx] = (uint16_t)run;
                run += hist[idx];
            }
        }
        __syncthreads();

        #pragma unroll
        for (int k = 0; k < 4; ++k) {
            if (dsts[k] >= 0) {
                const int bin = dsts[k] >> 6;
                const int pos = atomicAdd(&cur[bin], 1);   // LDS atomic
                stg[pos] = ((dsts[k] & 63) << 16) | srcs[k];
            }
        }
        __syncthreads();

        // coalesced stream-out: 1024 ints as 256 x int4
        ((int4*)(bucket + (size_t)blk * PEB))[t] = ((const int4*)stg)[t];
        return;
    }

    // ---- linear1 role ----
    for (int i = t; i < IN_CH * HIDDEN; i += 256) {
        int k = i / HIDDEN, c = i % HIDDEN;
        sW[k][c]      = W1l[i];
        sW[k][c + 16] = W1r[i];
    }

    const int node0 = (blockIdx.x - PB) * 32;
    for (int i = t; i < 32 * (IN_CH / 4); i += 256) {
        int r    = i / (IN_CH / 4);
        int col4 = i % (IN_CH / 4);
        int node = node0 + r;
        float4 v = make_float4(0.f, 0.f, 0.f, 0.f);
        if (node < N_NODES)
            v = ((const float4*)x)[node * (IN_CH / 4) + col4];
        sx[r][col4 * 4 + 0] = v.x;
        sx[r][col4 * 4 + 1] = v.y;
        sx[r][col4 * 4 + 2] = v.z;
        sx[r][col4 * 4 + 3] = v.w;
    }
    __syncthreads();

    const int r    = t & 31;
    const int og   = t >> 5;
    const int node = node0 + r;

    float4 acc = make_float4(0.f, 0.f, 0.f, 0.f);
    #pragma unroll 4
    for (int k = 0; k < IN_CH; ++k) {
        const float xv = sx[r][k];
        const float4 w4 = *(const float4*)&sW[k][og * 4];  // ds_read_b128
        acc.x += xv * w4.x;
        acc.y += xv * w4.y;
        acc.z += xv * w4.z;
        acc.w += xv * w4.w;
    }

    if (node < N_NODES) {
        const int oc = og * 4;
        float vals[4] = {acc.x, acc.y, acc.z, acc.w};
        #pragma unroll
        for (int j = 0; j < 4; ++j) {
            int o = oc + j;
            if (o < HIDDEN) y1[node * HIDDEN + o]            = vals[j];
            else            z1[node * HIDDEN + (o - HIDDEN)] = vals[j];
        }
    }
}

// ---------------------------------------------------------------------------
// K2: one block per bucket (256 thr).
//   Phase A (bin): gather this bucket's runs from all 782 part regions into
//   64-node LDS staging via LDS atomics; stream out row/cnt/ovf for K3.
//   Phase B (gather_h): 4 thr/node (quarter q=t&3) gather y1 rows using the
//   LDS-resident indices (no global row re-read), 4-deep ILP float4 loads;
//   h = relu(mean + b1 + z1) written float4 in place over z1.
// ---------------------------------------------------------------------------
__global__ __launch_bounds__(256) void k_bin_h(
    const int* __restrict__ bucket, const uint16_t* __restrict__ base16,
    uint16_t* __restrict__ row, int* __restrict__ cnt,
    int* __restrict__ govf, int* __restrict__ ovfcnt,
    const float* __restrict__ y1, float* __restrict__ z1h,
    const float* __restrict__ b1l)
{
    __shared__ __align__(16) uint16_t stg[64][ROWCAP];    // 6 KB
    __shared__ int cntl[64];
    __shared__ int ovfc;
    __shared__ int govf_l[OVFCAP];
    const int t = threadIdx.x;
    const int b = blockIdx.x;

    if (t < 64) cntl[t] = 0;
    if (t == 64) ovfc = 0;
    __syncthreads();

    // ---- phase A: bin ----
    for (int pb = t; pb < PB; pb += 256) {
        const int lo = base16[pb * 784 + b];
        const int hi = base16[pb * 784 + b + 1];
        const int* bp = bucket + (size_t)pb * PEB;
        for (int i = lo; i < hi; ++i) {
            const int w   = bp[i];
            const int nl  = (w >> 16) & 63;
            const int src = w & 0xFFFF;
            const int pos = atomicAdd(&cntl[nl], 1);       // LDS atomic
            if (pos < ROWCAP) {
                stg[nl][pos] = (uint16_t)src;
            } else {
                const int o = atomicAdd(&ovfc, 1);         // LDS atomic
                if (o < OVFCAP) { govf[b * OVFCAP + o] = w; govf_l[o] = w; }
            }
        }
    }
    __syncthreads();

    // stream out row/cnt/ovfcnt for K3 (overlaps with phase B issue)
    {
        const uint4* s4 = (const uint4*)stg;
        uint4* d4 = (uint4*)(row + (size_t)b * 64 * ROWCAP);
        for (int i = t; i < 384; i += 256) d4[i] = s4[i];
        if (t < 64) cnt[b * 64 + t] = cntl[t];
        if (t == 64) ovfcnt[b] = min(ovfc, OVFCAP);
    }

    // ---- phase B: gather y1 for own 64 nodes ----
    const int nl = t >> 2;                 // 0..63
    const int q  = t & 3;                  // feature quarter
    const int n  = b * 64 + nl;
    const int dgr   = cntl[nl];
    const int slots = dgr < ROWCAP ? dgr : ROWCAP;

    float4 s = make_float4(0.f, 0.f, 0.f, 0.f);
    int i = 0;
    for (; i + 4 <= slots; i += 4) {       // 4-deep ILP
        const int j0 = stg[nl][i + 0];
        const int j1 = stg[nl][i + 1];
        const int j2 = stg[nl][i + 2];
        const int j3 = stg[nl][i + 3];
        const float4 v0 = ((const float4*)(y1 + j0 * HIDDEN))[q];
        const float4 v1 = ((const float4*)(y1 + j1 * HIDDEN))[q];
        const float4 v2 = ((const float4*)(y1 + j2 * HIDDEN))[q];
        const float4 v3 = ((const float4*)(y1 + j3 * HIDDEN))[q];
        s.x += (v0.x + v1.x) + (v2.x + v3.x);
        s.y += (v0.y + v1.y) + (v2.y + v3.y);
        s.z += (v0.z + v1.z) + (v2.z + v3.z);
        s.w += (v0.w + v1.w) + (v2.w + v3.w);
    }
    for (; i < slots; ++i) {
        const int j = stg[nl][i];
        const float4 v = ((const float4*)(y1 + j * HIDDEN))[q];
        s.x += v.x; s.y += v.y; s.z += v.z; s.w += v.w;
    }

    if (dgr > ROWCAP) {                    // rare overflow, LDS-resident list
        const int on = min(ovfc, OVFCAP);
        for (int o = 0; o < on; ++o) {
            const int w = govf_l[o];
            if (((w >> 16) & 63) == nl) {
                const float4 v = ((const float4*)(y1 + (w & 0xFFFF) * HIDDEN))[q];
                s.x += v.x; s.y += v.y; s.z += v.z; s.w += v.w;
            }
        }
    }

    if (n < N_NODES) {
        const float inv = 1.0f / fmaxf((float)dgr, 1.0f);
        const float4 b4 = ((const float4*)b1l)[q];
        float4* zp = (float4*)(z1h + (size_t)n * HIDDEN) + q;
        const float4 z4 = *zp;
        float4 hv;
        hv.x = fmaxf(s.x * inv + b4.x + z4.x, 0.f);
        hv.y = fmaxf(s.y * inv + b4.y + z4.y, 0.f);
        hv.z = fmaxf(s.z * inv + b4.z + z4.z, 0.f);
        hv.w = fmaxf(s.w * inv + b4.w + z4.w, 0.f);
        *zp = hv;                          // in-place z1 -> h
    }
}

// ---------------------------------------------------------------------------
// K3: fused gather layer 2 + output (float4-quartered core, R16-identical).
// ---------------------------------------------------------------------------
__device__ __forceinline__ float4 gather_rows_f4(
    const float* __restrict__ feat, const uint16_t* __restrict__ rp,
    int slots, int ri, int q)
{
    float4 s = make_float4(0.f, 0.f, 0.f, 0.f);
    int i = 0;
    while (i + 16 < slots) {
        const int j0 = rp[i + ri];
        const int idx1 = i + 16 + ri;
        const bool p1 = idx1 < slots;
        const int j1 = p1 ? rp[idx1] : 0;
        const float4 v0 = ((const float4*)(feat + j0 * HIDDEN))[q];
        float4 v1 = make_float4(0.f, 0.f, 0.f, 0.f);
        if (p1) v1 = ((const float4*)(feat + j1 * HIDDEN))[q];
        s.x += v0.x + v1.x; s.y += v0.y + v1.y;
        s.z += v0.z + v1.z; s.w += v0.w + v1.w;
        i += 32;
    }
    if (i + ri < slots) {
        const int j = rp[i + ri];
        const float4 v = ((const float4*)(feat + j * HIDDEN))[q];
        s.x += v.x; s.y += v.y; s.z += v.z; s.w += v.w;
    }
    #pragma unroll
    for (int off = 4; off <= 32; off <<= 1) {
        s.x += __shfl_xor(s.x, off);
        s.y += __shfl_xor(s.y, off);
        s.z += __shfl_xor(s.z, off);
        s.w += __shfl_xor(s.w, off);
    }
    return s;
}

__global__ __launch_bounds__(1024) void k_out(
    const int* __restrict__ cnt, const uint16_t* __restrict__ row,
    const int* __restrict__ govf, const int* __restrict__ ovfcnt,
    const float* __restrict__ h,
    const float* __restrict__ W2l, const float* __restrict__ b2l,
    const float* __restrict__ W2r,
    float* __restrict__ out)
{
    __shared__ float sW[HIDDEN][2][OUT_CH];   // 8 KiB
    __shared__ float sm[16][HIDDEN];
    __shared__ float sh[16][HIDDEN];
    const int t = threadIdx.x;

    const int lane = t & 63;
    const int wid  = t >> 6;
    const int n = blockIdx.x * 16 + wid;      // 3125 * 16 = exactly 50000
    const int q  = lane & 3;
    const int ri = lane >> 2;

    const int dgr   = cnt[n];
    const int slots = dgr < ROWCAP ? dgr : ROWCAP;
    const uint16_t* rp = row + (size_t)n * ROWCAP;

    float4 s = gather_rows_f4(h, rp, slots, ri, q);

    if (dgr > ROWCAP) {
        const int b = n >> 6;
        const int on = ovfcnt[b];
        for (int o = 0; o < on; ++o) {
            const int w = govf[b * OVFCAP + o];
            if (((w >> 16) & 63) == (n & 63)) {
                const float4 v = ((const float4*)(h + (w & 0xFFFF) * HIDDEN))[q];
                s.x += v.x; s.y += v.y; s.z += v.z; s.w += v.w;
            }
        }
    }

    if (lane < 4) {
        const float inv = 1.0f / fmaxf((float)dgr, 1.0f);
        float4 m4;
        m4.x = s.x * inv; m4.y = s.y * inv; m4.z = s.z * inv; m4.w = s.w * inv;
        ((float4*)&sm[wid][0])[q] = m4;
        ((float4*)&sh[wid][0])[q] = ((const float4*)(h + (size_t)n * HIDDEN))[q];
    }

    {
        const int k = t / OUT_CH, c2 = t % OUT_CH;
        sW[k][0][c2] = W2l[t];
        sW[k][1][c2] = W2r[t];
    }
    __syncthreads();

    float acc = b2l[lane];
    #pragma unroll
    for (int k = 0; k < HIDDEN; ++k)
        acc += sm[wid][k] * sW[k][0][lane] + sh[wid][k] * sW[k][1][lane];

    float mx = acc;
    #pragma unroll
    for (int off = 32; off > 0; off >>= 1)
        mx = fmaxf(mx, __shfl_xor(mx, off));
    float ex = expf(acc - mx);
    float sum = ex;
    #pragma unroll
    for (int off = 32; off > 0; off >>= 1)
        sum += __shfl_xor(sum, off);

    out[(size_t)n * OUT_CH + lane] = acc - mx - logf(sum);
}

// ---------------------------------------------------------------------------
extern "C" void kernel_launch(void* const* d_in, const int* in_sizes, int n_in,
                              void* d_out, int out_size, void* d_ws, size_t ws_size,
                              hipStream_t stream)
{
    const float* x   = (const float*)d_in[0];
    const float* W1l = (const float*)d_in[1];
    const float* b1l = (const float*)d_in[2];
    const float* W1r = (const float*)d_in[3];
    const float* W2l = (const float*)d_in[4];
    const float* b2l = (const float*)d_in[5];
    const float* W2r = (const float*)d_in[6];
    const int*   ei  = (const int*)d_in[7];
    float* out = (float*)d_out;

    const size_t NH = (size_t)N_NODES * HIDDEN;           // 800000
    int*   bucket = (int*)d_ws;                           // [PB*PEB]    3.2 MB
    float* bufA   = (float*)(bucket + (size_t)PB * PEB);  // y1          3.2 MB
    float* bufB   = bufA + NH;                            // z1 -> h     3.2 MB
    int*   cnt    = (int*)(bufB + NH);                    // [NPAD]      0.2 MB
    int*   govf   = cnt + NPAD;                           // [NBB*64]    0.2 MB
    int*   ovfcnt = govf + NBB * OVFCAP;                  // [NBB]
    uint16_t* base16 = (uint16_t*)(ovfcnt + NBB + 2);     // [PB*784]    1.23 MB
    uint16_t* row    = base16 + (size_t)PB * 784;         // [NPAD*48]   4.8 MB

    // K1: partition (blocks 0..PB-1) || linear1 (blocks PB..PB+LB-1)
    k_front<<<PB + LB, 256, 0, stream>>>(ei, bucket, base16,
                                         x, W1l, W1r, bufA, bufB);

    // K2: bin + gather_h fused per bucket (row stays in LDS for the gather)
    k_bin_h<<<NBB, 256, 0, stream>>>(bucket, base16, row, cnt, govf, ovfcnt,
                                     bufA, bufB, b1l);

    // K3: fused gather2 + linear2 + log_softmax
    k_out<<<N_NODES / 16, 1024, 0, stream>>>(cnt, row, govf, ovfcnt, bufB,
                                             W2l, b2l, W2r, out);
}